// Round 6
// baseline (2075.822 us; speedup 1.0000x reference)
//
#include <hip/hip_runtime.h>
#include <hip/hip_bf16.h>

#define NN 50000
#define NE 800000
#define NG 50

typedef unsigned int u32;

// ---------------- detect int64 vs int32 edge_index encoding ----------------
__global__ void k_detect(const int* __restrict__ ei_raw, int* flag) {
    if (blockIdx.x == 0 && threadIdx.x == 0) {
        int z = 0;
        for (int i = 0; i < 256; i++) if (ei_raw[2 * i + 1] == 0) z++;
        *flag = (z >= 128) ? 1 : 0;
    }
}

// ---------------- convert edge_index & batch to int32 ----------------
__global__ void k_cvt(const int* __restrict__ ei_raw, const int* __restrict__ batch_raw,
                      const int* __restrict__ flag, int* __restrict__ src,
                      int* __restrict__ dst, int* __restrict__ batch32) {
    int i = blockIdx.x * blockDim.x + threadIdx.x;
    int w = *flag;
    if (i < NE) {
        if (w) { src[i] = ei_raw[2 * i]; dst[i] = ei_raw[2 * (NE + i)]; }
        else   { src[i] = ei_raw[i];     dst[i] = ei_raw[NE + i]; }
    }
    if (i < NN) batch32[i] = w ? batch_raw[2 * i] : batch_raw[i];
}

// ---------------- init graph bounds ----------------
__global__ void k_initb(int* startg, int* endg) {
    int i = blockIdx.x * blockDim.x + threadIdx.x;
    if (i < NG) { startg[i] = 0x7fffffff; endg[i] = 0; }
}

// ---------------- zero agg + deg ----------------
__global__ void k_zero(float* agg, int* degi) {
    int i = blockIdx.x * blockDim.x + threadIdx.x;
    if (i < NN * 64) agg[i] = 0.f;
    if (i < NN) degi[i] = 0;
}

// ---------------- xg[n][j] = sum_d x[n][d] * g[d][j], j in [0,256) ----------------
__global__ __launch_bounds__(256) void k_xg(const float* __restrict__ x,
                                            const float* __restrict__ g,
                                            float* __restrict__ xg) {
    __shared__ float xs[4][64];
    int n0 = blockIdx.x * 4;
    int j = threadIdx.x;
    {
        int r = j >> 6, d = j & 63;
        int n = n0 + r;
        xs[r][d] = (n < NN) ? x[(size_t)n * 64 + d] : 0.f;
    }
    __syncthreads();
    float a0 = 0.f, a1 = 0.f, a2 = 0.f, a3 = 0.f;
    for (int d = 0; d < 64; d++) {
        float gv = g[d * 256 + j];
        a0 += xs[0][d] * gv; a1 += xs[1][d] * gv;
        a2 += xs[2][d] * gv; a3 += xs[3][d] * gv;
    }
    if (n0 + 0 < NN) xg[(size_t)(n0 + 0) * 256 + j] = a0;
    if (n0 + 1 < NN) xg[(size_t)(n0 + 1) * 256 + j] = a1;
    if (n0 + 2 < NN) xg[(size_t)(n0 + 2) * 256 + j] = a2;
    if (n0 + 3 < NN) xg[(size_t)(n0 + 3) * 256 + j] = a3;
}

// ---------------- per-edge message + scatter-add (literal reference) ----------------
__global__ __launch_bounds__(256) void k_msg(const float* __restrict__ xg,
                                             const int* __restrict__ src,
                                             const int* __restrict__ dst,
                                             const float* __restrict__ eattr,
                                             const float* __restrict__ mu,
                                             const float* __restrict__ sg,
                                             float* __restrict__ agg, int* __restrict__ degi) {
    int e = (blockIdx.x * 256 + threadIdx.x) >> 6;
    int lane = threadIdx.x & 63;
    if (e >= NE) return;
    float a0 = eattr[2 * e], a1 = eattr[2 * e + 1];
    int s = src[e], d = dst[e];
    float m = 0.f;
#pragma unroll
    for (int k = 0; k < 4; k++) {
        float d0 = a0 - mu[2 * k], d1 = a1 - mu[2 * k + 1];
        float s0 = sg[2 * k], s1 = sg[2 * k + 1];
        float t = d0 * d0 / (1e-15f + s0 * s0) + d1 * d1 / (1e-15f + s1 * s1);
        float w = expf(-0.5f * t);
        m += w * xg[(size_t)s * 256 + k * 64 + lane];
    }
    atomicAdd(&agg[(size_t)d * 64 + lane], m);
    if (lane == 0) atomicAdd(&degi[d], 1);
}

// ---------------- post: out = lrelu(agg/deg + x@rw + b); opt x3 = x0 + out ----------------
__global__ __launch_bounds__(256) void k_post(const float* __restrict__ agg,
                                              const int* __restrict__ degi,
                                              const float* __restrict__ x,
                                              const float* __restrict__ rw,
                                              const float* __restrict__ b,
                                              float* __restrict__ xout,
                                              const float* __restrict__ xadd,
                                              float* __restrict__ x3out) {
    int gid = blockIdx.x * 256 + threadIdx.x;
    if (gid >= NN * 64) return;
    int n = gid >> 6, h = gid & 63;
    int dg = degi[n];
    float sc = 1.f / (float)(dg > 1 ? dg : 1);
    float acc = agg[gid] * sc + b[h];
    const float* xr = x + (size_t)n * 64;
#pragma unroll 8
    for (int d = 0; d < 64; d++) acc += xr[d] * rw[d * 64 + h];
    float v = acc > 0.f ? acc : 0.01f * acc;
    xout[gid] = v;
    if (x3out) x3out[gid] = v + xadd[gid];
}

// ---------------- per-graph node ranges ----------------
__global__ void k_bounds(const int* __restrict__ batch, int* startg, int* endg) {
    int n = blockIdx.x * blockDim.x + threadIdx.x;
    if (n >= NN) return;
    int b = batch[n];
    atomicMin(&startg[b], n);
    atomicMax(&endg[b], n + 1);
}

// ---------------- segment max pool over concat [x4,x1,x2,x3] (fp32) ----------------
__global__ void k_pool(const float* __restrict__ x4, const float* __restrict__ x1,
                       const float* __restrict__ x2, const float* __restrict__ x3,
                       const int* __restrict__ startg, const int* __restrict__ endg,
                       float* __restrict__ pooled) {
    int g = blockIdx.x;
    int c = threadIdx.x;
    const float* arr = (c < 64) ? x4 : (c < 128) ? x1 : (c < 192) ? x2 : x3;
    int h = c & 63;
    int s = startg[g], e = endg[g];
    float m = -3.4e38f;
    for (int n = s; n < e; n++) {
        float v = arr[(size_t)n * 64 + h];
        m = v > m ? v : m;
    }
    pooled[g * 256 + c] = m;
}

// ---------------- final MLP: (50,256)@(256,64) -> BN -> relu -> (64,10), fp32 OUT ----------------
__global__ void k_final(const float* __restrict__ pooled, const float* __restrict__ w1,
                        const float* __restrict__ b1, const float* __restrict__ gamma,
                        const float* __restrict__ beta, const float* __restrict__ w2,
                        const float* __restrict__ b2v, float* __restrict__ out) {
    __shared__ float zsh[64];
    int g = blockIdx.x, h = threadIdx.x;
    float z = b1[h];
    const float* p = pooled + g * 256;
    for (int j = 0; j < 256; j++) z += p[j] * w1[j * 64 + h];
    z = z * 0.9999950000374997f * gamma[h] + beta[h];  // /sqrt(1+1e-5)
    z = z > 0.f ? z : 0.f;
    zsh[h] = z;
    __syncthreads();
    if (h < 10) {
        float o = b2v[h];
        for (int k = 0; k < 64; k++) o += zsh[k] * w2[k * 10 + h];
        out[g * 10 + h] = o;   // fp32 output — reference output dtype is float32
    }
}

extern "C" void kernel_launch(void* const* d_in, const int* in_sizes, int n_in,
                              void* d_out, int out_size, void* d_ws, size_t ws_size,
                              hipStream_t stream) {
    const float* x_in    = (const float*)d_in[0];
    const int* ei_raw    = (const int*)d_in[1];
    const int* batch_raw = (const int*)d_in[2];
    const float* eattr   = (const float*)d_in[3];

    const float *g_[4], *mu_[4], *sg_[4], *rw_[4], *b_[4];
    for (int i = 0; i < 4; i++) {
        g_[i]  = (const float*)d_in[4 + 5 * i + 0];
        mu_[i] = (const float*)d_in[4 + 5 * i + 1];
        sg_[i] = (const float*)d_in[4 + 5 * i + 2];
        rw_[i] = (const float*)d_in[4 + 5 * i + 3];
        b_[i]  = (const float*)d_in[4 + 5 * i + 4];
    }
    const float* w_mlp1 = (const float*)d_in[24];
    const float* b_mlp1 = (const float*)d_in[25];
    const float* bn_g   = (const float*)d_in[26];
    const float* bn_b   = (const float*)d_in[27];
    const float* w_mlp2 = (const float*)d_in[28];
    const float* b_mlp2 = (const float*)d_in[29];
    float* out = (float*)d_out;

    // workspace carve-up (~135 MB)
    char* ws = (char*)d_ws;
    size_t o = 0;
    auto take = [&](size_t bytes) { size_t r = o; o += (bytes + 255) & ~(size_t)255; return r; };
    int*   flag    = (int*)(ws + take(4));
    int*   src     = (int*)(ws + take((size_t)NE * 4));
    int*   dst     = (int*)(ws + take((size_t)NE * 4));
    int*   batch32 = (int*)(ws + take((size_t)NN * 4));
    float* xg      = (float*)(ws + take((size_t)NN * 256 * 4));
    float* agg     = (float*)(ws + take((size_t)NN * 64 * 4));
    int*   degi    = (int*)(ws + take((size_t)NN * 4));
    float* x0      = (float*)(ws + take((size_t)NN * 64 * 4));
    float* x1      = (float*)(ws + take((size_t)NN * 64 * 4));
    float* x2      = (float*)(ws + take((size_t)NN * 64 * 4));
    float* x3      = (float*)(ws + take((size_t)NN * 64 * 4));
    float* x4      = (float*)(ws + take((size_t)NN * 64 * 4));
    float* pooled  = (float*)(ws + take((size_t)NG * 256 * 4));
    int*   startg  = (int*)(ws + take(NG * 4));
    int*   endg    = (int*)(ws + take(NG * 4));
    (void)ws_size; (void)in_sizes; (void)n_in; (void)out_size;

    // index dtype normalization
    k_detect<<<dim3(1), dim3(64), 0, stream>>>(ei_raw, flag);
    k_cvt<<<dim3((NE + 255) / 256), dim3(256), 0, stream>>>(ei_raw, batch_raw, flag, src, dst, batch32);
    k_initb<<<dim3(1), dim3(64), 0, stream>>>(startg, endg);

    const int nodeGrid = (NN * 64 + 255) / 256;
    const int xgGrid   = (NN + 3) / 4;
    const int msgGrid  = (NE * 64) / 256;

    const float* lin[4]  = {x_in, x0, x1, x3};
    float*       lout[4] = {x0, x1, x2, x4};
    for (int l = 0; l < 4; l++) {
        k_zero<<<dim3(nodeGrid), dim3(256), 0, stream>>>(agg, degi);
        k_xg<<<dim3(xgGrid), dim3(256), 0, stream>>>(lin[l], g_[l], xg);
        k_msg<<<dim3(msgGrid), dim3(256), 0, stream>>>(xg, src, dst, eattr, mu_[l], sg_[l], agg, degi);
        k_post<<<dim3(nodeGrid), dim3(256), 0, stream>>>(
            agg, degi, lin[l], rw_[l], b_[l], lout[l],
            (l == 2) ? x0 : (const float*)nullptr,
            (l == 2) ? x3 : (float*)nullptr);
    }

    k_bounds<<<dim3((NN + 255) / 256), dim3(256), 0, stream>>>(batch32, startg, endg);
    k_pool<<<dim3(NG), dim3(256), 0, stream>>>(x4, x1, x2, x3, startg, endg, pooled);
    k_final<<<dim3(NG), dim3(64), 0, stream>>>(pooled, w_mlp1, b_mlp1, bn_g, bn_b, w_mlp2, b_mlp2, out);
}

// Round 7
// 1033.258 us; speedup vs baseline: 2.0090x; 2.0090x over previous
//
#include <hip/hip_runtime.h>
#include <hip/hip_bf16.h>

#define NN 50000
#define NE 800000
#define NG 50
#define NSL 16   // pool slices per graph

typedef unsigned short u16;
typedef unsigned int u32;
typedef __attribute__((ext_vector_type(8))) short short8;
typedef __attribute__((ext_vector_type(4))) float float4v;

__device__ __forceinline__ float b2f(u16 u) {
    union { u32 i; float f; } v; v.i = ((u32)u) << 16; return v.f;
}
__device__ __forceinline__ u16 f2b(float f) {
    union { float f; u32 i; } v; v.f = f;
    u32 i = v.i;
    return (u16)((i + 0x7FFFu + ((i >> 16) & 1u)) >> 16);
}

// ---------------- detect int64 vs int32 edge_index encoding ----------------
__global__ void k_detect(const int* __restrict__ ei_raw, int* flag) {
    if (blockIdx.x == 0 && threadIdx.x == 0) {
        int z = 0;
        for (int i = 0; i < 256; i++) if (ei_raw[2 * i + 1] == 0) z++;
        *flag = (z >= 128) ? 1 : 0;
    }
}

// ---------------- convert edge_index & batch to int32 ----------------
__global__ void k_cvt(const int* __restrict__ ei_raw, const int* __restrict__ batch_raw,
                      const int* __restrict__ flag, int* __restrict__ src,
                      int* __restrict__ dst, int* __restrict__ batch32) {
    int i = blockIdx.x * blockDim.x + threadIdx.x;
    int w = *flag;
    if (i < NE) {
        if (w) { src[i] = ei_raw[2 * i]; dst[i] = ei_raw[2 * (NE + i)]; }
        else   { src[i] = ei_raw[i];     dst[i] = ei_raw[NE + i]; }
    }
    if (i < NN) batch32[i] = w ? batch_raw[2 * i] : batch_raw[i];
}

// ---------------- init ----------------
__global__ void k_init(int* cnt, int* startg, int* endg) {
    int i = blockIdx.x * blockDim.x + threadIdx.x;
    if (i < NN) cnt[i] = 0;
    if (i < NG) { startg[i] = 0x7fffffff; endg[i] = 0; }
}

// ---------------- histogram of dst ----------------
__global__ void k_hist(const int* __restrict__ dst, int* cnt) {
    int e = blockIdx.x * blockDim.x + threadIdx.x;
    if (e < NE) atomicAdd(&cnt[dst[e]], 1);
}

// ---------------- single-block exclusive scan over 50000 ints ----------------
__global__ void k_scan(int* cnt, int* off) {
    __shared__ int s[1024];
    int t = threadIdx.x;
    int base = t * 49;
    int local = 0;
    for (int i = 0; i < 49; i++) {
        int idx = base + i;
        if (idx < NN) local += cnt[idx];
    }
    s[t] = local; __syncthreads();
    for (int d = 1; d < 1024; d <<= 1) {
        int v = s[t];
        int a = (t >= d) ? s[t - d] : 0;
        __syncthreads();
        s[t] = v + a;
        __syncthreads();
    }
    int run = s[t] - local;  // exclusive prefix
    for (int i = 0; i < 49; i++) {
        int idx = base + i;
        if (idx < NN) {
            int c = cnt[idx];
            off[idx] = run;
            run += c;
            cnt[idx] = 0;   // reset for scatter cursor
            if (idx == NN - 1) off[NN] = run;
        }
    }
}

// ---------------- scatter edges into CSR-by-dst ----------------
__global__ void k_scatter(const int* __restrict__ src, const int* __restrict__ dst,
                          const float* __restrict__ eattr, const int* __restrict__ off,
                          int* cur, int* __restrict__ csr_src, float* __restrict__ csr_attr) {
    int e = blockIdx.x * blockDim.x + threadIdx.x;
    if (e >= NE) return;
    int d = dst[e];
    int p = atomicAdd(&cur[d], 1);
    int slot = off[d] + p;
    csr_src[slot] = src[e];
    csr_attr[2 * slot]     = eattr[2 * e];
    csr_attr[2 * slot + 1] = eattr[2 * e + 1];
}

// ---------------- x (f32) -> bf16 ----------------
__global__ void k_x2b(const float* __restrict__ x, u16* __restrict__ xb) {
    int i = blockIdx.x * blockDim.x + threadIdx.x;
    if (i < NN * 64) xb[i] = f2b(x[i]);
}

// ---------------- Gaussian weights for ONE layer, CSR order, fp32 ----------------
__global__ void k_gw(const float* __restrict__ csr_attr, const float* __restrict__ mu,
                     const float* __restrict__ sg, float* __restrict__ gw) {
    int j = blockIdx.x * blockDim.x + threadIdx.x;
    if (j >= NE) return;
    float a0 = csr_attr[2 * j], a1 = csr_attr[2 * j + 1];
    float o[4];
#pragma unroll
    for (int k = 0; k < 4; k++) {
        float d0 = a0 - mu[2 * k], d1 = a1 - mu[2 * k + 1];
        float s0 = sg[2 * k], s1 = sg[2 * k + 1];
        float t = d0 * d0 / (1e-15f + s0 * s0) + d1 * d1 / (1e-15f + s1 * s1);
        o[k] = expf(-0.5f * t);
    }
    *(float4*)(gw + (size_t)j * 4) = make_float4(o[0], o[1], o[2], o[3]);
}

// ---------------- pre-swizzle Wcat=[G2;rw] (f32) into bf16 MFMA B-fragment order ----------------
// bsw layout per layer: [(kt*4+ct)*64 + lane] 16B chunks; chunk elem j = Wcat[kt*32+(lane>>4)*8+j][ct*16+(lane&15)]
struct WParams { const float* g[4]; const float* rw[4]; };
__global__ void k_wprep(WParams P, u16* __restrict__ bsw) {
    int id = blockIdx.x * blockDim.x + threadIdx.x;
    if (id >= 4 * 20480) return;
    int l = id / 20480, r = id % 20480;
    int j = r & 7, lane = (r >> 3) & 63, ctkt = r >> 9;
    int ct = ctkt & 3, kt = ctkt >> 2;
    int k = kt * 32 + (lane >> 4) * 8 + j;
    int n = ct * 16 + (lane & 15);
    float v;
    if (k < 256) v = P.g[l][(k & 63) * 256 + (k >> 6) * 64 + n];  // G2[k][n] = g[d][kk*64+n]
    else         v = P.rw[l][(k - 256) * 64 + n];
    bsw[id] = f2b(v);
}

// ---------------- aggregation: y[n][k*64+d] = (1/deg) sum_e gw[e][k]*x[src][d] ----------------
__global__ __launch_bounds__(256) void k_agg(const u16* __restrict__ xin,
                                             const int* __restrict__ csr_src,
                                             const float4* __restrict__ gw,
                                             const int* __restrict__ off,
                                             u16* __restrict__ y) {
    int wid = (blockIdx.x * 256 + threadIdx.x) >> 6;  // node, one wave each
    int lane = threadIdx.x & 63;                       // feature d
    if (wid >= NN) return;
    int beg = off[wid], end = off[wid + 1];
    float a0 = 0.f, a1 = 0.f, a2 = 0.f, a3 = 0.f;
#pragma unroll 2
    for (int j = beg; j < end; j++) {
        int s = csr_src[j];
        float4 w = gw[j];
        float xv = b2f(xin[(size_t)s * 64 + lane]);
        a0 += w.x * xv; a1 += w.y * xv; a2 += w.z * xv; a3 += w.w * xv;
    }
    int deg = end - beg;
    float sc = 1.0f / (float)(deg > 1 ? deg : 1);
    size_t o = (size_t)wid * 256 + lane;
    y[o]       = f2b(a0 * sc);
    y[o + 64]  = f2b(a1 * sc);
    y[o + 128] = f2b(a2 * sc);
    y[o + 192] = f2b(a3 * sc);
}

// ---------------- GEMM: xout = lrelu([y|xin](N,320) @ Wcat(320,64) + b); opt x3 = x0 + xout ----------------
#define LDA 328  // 320 + 8 u16 pad -> rows 656B, 16B aligned
__global__ __launch_bounds__(256) void k_gemm(const u16* __restrict__ y,
                                              const u16* __restrict__ xin,
                                              const u16* __restrict__ bsw,
                                              const float* __restrict__ bias,
                                              u16* __restrict__ xout,
                                              const u16* __restrict__ xadd,
                                              u16* __restrict__ x3out) {
    __shared__ u16 As[64 * LDA];
    int t = threadIdx.x;
    int rbase = blockIdx.x * 64;
    // cooperative stage A = [y | xin] rows rbase..rbase+63 (2560 x 16B chunks)
#pragma unroll
    for (int c = 0; c < 10; c++) {
        int idx = t + c * 256;
        int row = idx / 40, pos = idx % 40;
        int grow = rbase + row;
        uint4 v = make_uint4(0, 0, 0, 0);
        if (grow < NN) {
            if (pos < 32) v = *(const uint4*)(y + (size_t)grow * 256 + pos * 8);
            else          v = *(const uint4*)(xin + (size_t)grow * 64 + (pos - 32) * 8);
        }
        *(uint4*)(&As[row * LDA + pos * 8]) = v;
    }
    __syncthreads();

    int wave = t >> 6, lane = t & 63, lr = lane & 15, lg = lane >> 4;
    float4v acc0 = {0.f,0.f,0.f,0.f}, acc1 = {0.f,0.f,0.f,0.f};
    float4v acc2 = {0.f,0.f,0.f,0.f}, acc3 = {0.f,0.f,0.f,0.f};
    const u16* ar = &As[(wave * 16 + lr) * LDA + lg * 8];
    const uint4* bp = (const uint4*)bsw;
    for (int kt = 0; kt < 10; kt++) {
        short8 a  = *(const short8*)(ar + kt * 32);
        short8 b0 = *(const short8*)(bp + (kt * 4 + 0) * 64 + lane);
        short8 b1 = *(const short8*)(bp + (kt * 4 + 1) * 64 + lane);
        short8 b2 = *(const short8*)(bp + (kt * 4 + 2) * 64 + lane);
        short8 b3 = *(const short8*)(bp + (kt * 4 + 3) * 64 + lane);
        acc0 = __builtin_amdgcn_mfma_f32_16x16x32_bf16(a, b0, acc0, 0, 0, 0);
        acc1 = __builtin_amdgcn_mfma_f32_16x16x32_bf16(a, b1, acc1, 0, 0, 0);
        acc2 = __builtin_amdgcn_mfma_f32_16x16x32_bf16(a, b2, acc2, 0, 0, 0);
        acc3 = __builtin_amdgcn_mfma_f32_16x16x32_bf16(a, b3, acc3, 0, 0, 0);
    }
    float4v accs[4] = {acc0, acc1, acc2, acc3};
#pragma unroll
    for (int ct = 0; ct < 4; ct++) {
        int col = ct * 16 + lr;
        float bv = bias[col];
#pragma unroll
        for (int reg = 0; reg < 4; reg++) {
            int grow = rbase + wave * 16 + lg * 4 + reg;  // C/D: row=(lane>>4)*4+reg, col=lane&15
            if (grow < NN) {
                float v = accs[ct][reg] + bv;
                v = v > 0.f ? v : 0.01f * v;
                xout[(size_t)grow * 64 + col] = f2b(v);
                if (x3out) {
                    float s2 = v + b2f(xadd[(size_t)grow * 64 + col]);
                    x3out[(size_t)grow * 64 + col] = f2b(s2);
                }
            }
        }
    }
}

// ---------------- per-graph node ranges ----------------
__global__ void k_bounds(const int* __restrict__ batch, int* startg, int* endg) {
    int n = blockIdx.x * blockDim.x + threadIdx.x;
    if (n >= NN) return;
    int b = batch[n];
    atomicMin(&startg[b], n);
    atomicMax(&endg[b], n + 1);
}

// ---------------- pool stage 1: partial max over node slice, concat [x4,x1,x2,x3] ----------------
__global__ __launch_bounds__(256) void k_pool1(const u16* __restrict__ x4, const u16* __restrict__ x1,
                                               const u16* __restrict__ x2, const u16* __restrict__ x3,
                                               const int* __restrict__ startg, const int* __restrict__ endg,
                                               float* __restrict__ partial) {
    int g = blockIdx.x, sl = blockIdx.y;
    int c = threadIdx.x;
    const u16* arr = (c < 64) ? x4 : (c < 128) ? x1 : (c < 192) ? x2 : x3;
    int h = c & 63;
    int s = startg[g], e = endg[g];
    int len = e - s;
    int chunk = (len + NSL - 1) / NSL;
    int s0 = s + sl * chunk;
    int e0 = s0 + chunk; if (e0 > e) e0 = e;
    float m = -3.4e38f;
    for (int n = s0; n < e0; n++) {
        float v = b2f(arr[(size_t)n * 64 + h]);
        m = v > m ? v : m;
    }
    partial[((size_t)g * NSL + sl) * 256 + c] = m;
}

// ---------------- pool stage 2: reduce slices ----------------
__global__ __launch_bounds__(256) void k_pool2(const float* __restrict__ partial,
                                               float* __restrict__ pooled) {
    int g = blockIdx.x, c = threadIdx.x;
    float m = -3.4e38f;
#pragma unroll
    for (int sl = 0; sl < NSL; sl++) {
        float v = partial[((size_t)g * NSL + sl) * 256 + c];
        m = v > m ? v : m;
    }
    pooled[g * 256 + c] = m;
}

// ---------------- final MLP: (50,256)@(256,64) -> BN -> relu -> (64,10), fp32 OUT ----------------
__global__ void k_final(const float* __restrict__ pooled, const float* __restrict__ w1,
                        const float* __restrict__ b1, const float* __restrict__ gamma,
                        const float* __restrict__ beta, const float* __restrict__ w2,
                        const float* __restrict__ b2v, float* __restrict__ out) {
    __shared__ float zsh[64];
    int g = blockIdx.x, h = threadIdx.x;
    float z = b1[h];
    const float* p = pooled + g * 256;
    for (int j = 0; j < 256; j++) z += p[j] * w1[j * 64 + h];
    z = z * 0.9999950000374997f * gamma[h] + beta[h];  // /sqrt(1+1e-5)
    z = z > 0.f ? z : 0.f;
    zsh[h] = z;
    __syncthreads();
    if (h < 10) {
        float o = b2v[h];
        for (int k = 0; k < 64; k++) o += zsh[k] * w2[k * 10 + h];
        out[g * 10 + h] = o;   // fp32 output
    }
}

extern "C" void kernel_launch(void* const* d_in, const int* in_sizes, int n_in,
                              void* d_out, int out_size, void* d_ws, size_t ws_size,
                              hipStream_t stream) {
    const float* x_in    = (const float*)d_in[0];
    const int* ei_raw    = (const int*)d_in[1];
    const int* batch_raw = (const int*)d_in[2];
    const float* eattr   = (const float*)d_in[3];

    const float *g_[4], *mu_[4], *sg_[4], *rw_[4], *b_[4];
    for (int i = 0; i < 4; i++) {
        g_[i]  = (const float*)d_in[4 + 5 * i + 0];
        mu_[i] = (const float*)d_in[4 + 5 * i + 1];
        sg_[i] = (const float*)d_in[4 + 5 * i + 2];
        rw_[i] = (const float*)d_in[4 + 5 * i + 3];
        b_[i]  = (const float*)d_in[4 + 5 * i + 4];
    }
    const float* w_mlp1 = (const float*)d_in[24];
    const float* b_mlp1 = (const float*)d_in[25];
    const float* bn_g   = (const float*)d_in[26];
    const float* bn_b   = (const float*)d_in[27];
    const float* w_mlp2 = (const float*)d_in[28];
    const float* b_mlp2 = (const float*)d_in[29];
    float* out = (float*)d_out;

    // workspace carve-up (~46 MB)
    char* ws = (char*)d_ws;
    size_t o = 0;
    auto take = [&](size_t bytes) { size_t r = o; o += (bytes + 255) & ~(size_t)255; return r; };
    int*   flag     = (int*)(ws + take(4));
    int*   src      = (int*)(ws + take((size_t)NE * 4));
    int*   dst      = (int*)(ws + take((size_t)NE * 4));
    int*   batch32  = (int*)(ws + take((size_t)NN * 4));
    int*   off      = (int*)(ws + take((NN + 1) * 4));
    int*   cnt      = (int*)(ws + take((size_t)NN * 4));
    int*   csr_src  = (int*)(ws + take((size_t)NE * 4));
    float* csr_attr = (float*)(ws + take((size_t)NE * 8));
    float* gw       = (float*)(ws + take((size_t)NE * 16));      // one layer at a time
    u16*   xb       = (u16*)(ws + take((size_t)NN * 64 * 2));
    u16*   y        = (u16*)(ws + take((size_t)NN * 256 * 2));
    u16*   x0       = (u16*)(ws + take((size_t)NN * 64 * 2));
    u16*   x1       = (u16*)(ws + take((size_t)NN * 64 * 2));
    u16*   x2       = (u16*)(ws + take((size_t)NN * 64 * 2));
    u16*   x3       = (u16*)(ws + take((size_t)NN * 64 * 2));
    u16*   x4       = (u16*)(ws + take((size_t)NN * 64 * 2));
    u16*   bsw      = (u16*)(ws + take((size_t)4 * 320 * 64 * 2));
    float* partial  = (float*)(ws + take((size_t)NG * NSL * 256 * 4));
    float* pooled   = (float*)(ws + take((size_t)NG * 256 * 4));
    int*   startg   = (int*)(ws + take(NG * 4));
    int*   endg     = (int*)(ws + take(NG * 4));
    (void)ws_size; (void)in_sizes; (void)n_in; (void)out_size;

    // index dtype normalization
    k_detect<<<dim3(1), dim3(64), 0, stream>>>(ei_raw, flag);
    k_cvt<<<dim3((NE + 255) / 256), dim3(256), 0, stream>>>(ei_raw, batch_raw, flag, src, dst, batch32);

    // CSR build
    k_init<<<dim3((NN + 255) / 256), dim3(256), 0, stream>>>(cnt, startg, endg);
    k_hist<<<dim3(NE / 256), dim3(256), 0, stream>>>(dst, cnt);
    k_scan<<<dim3(1), dim3(1024), 0, stream>>>(cnt, off);
    k_scatter<<<dim3(NE / 256), dim3(256), 0, stream>>>(src, dst, eattr, off, cnt, csr_src, csr_attr);
    k_x2b<<<dim3((NN * 64 + 255) / 256), dim3(256), 0, stream>>>(x_in, xb);

    WParams WP;
    for (int i = 0; i < 4; i++) { WP.g[i] = g_[i]; WP.rw[i] = rw_[i]; }
    k_wprep<<<dim3(4 * 20480 / 256), dim3(256), 0, stream>>>(WP, bsw);

    const int aggGrid = NN / 4;            // 4 waves (nodes) per 256-thr block
    const int gemmGrid = (NN + 63) / 64;   // 64 rows per block

    const u16* lin[4]  = {xb, x0, x1, x3};
    u16*       lout[4] = {x0, x1, x2, x4};
    for (int l = 0; l < 4; l++) {
        k_gw<<<dim3(NE / 256), dim3(256), 0, stream>>>(csr_attr, mu_[l], sg_[l], gw);
        k_agg<<<dim3(aggGrid), dim3(256), 0, stream>>>(
            lin[l], csr_src, (const float4*)gw, off, y);
        k_gemm<<<dim3(gemmGrid), dim3(256), 0, stream>>>(
            y, lin[l], bsw + (size_t)l * 20480, b_[l], lout[l],
            (l == 2) ? x0 : (const u16*)nullptr,
            (l == 2) ? x3 : (u16*)nullptr);
    }

    k_bounds<<<dim3((NN + 255) / 256), dim3(256), 0, stream>>>(batch32, startg, endg);
    k_pool1<<<dim3(NG, NSL), dim3(256), 0, stream>>>(x4, x1, x2, x3, startg, endg, partial);
    k_pool2<<<dim3(NG), dim3(256), 0, stream>>>(partial, pooled);
    k_final<<<dim3(NG), dim3(64), 0, stream>>>(pooled, w_mlp1, b_mlp1, bn_g, bn_b, w_mlp2, b_mlp2, out);
}

// Round 8
// 710.850 us; speedup vs baseline: 2.9202x; 1.4536x over previous
//
#include <hip/hip_runtime.h>
#include <hip/hip_bf16.h>

#define NN 50000
#define NE 800000
#define NG 50
#define NSL 16   // pool slices per graph

typedef unsigned short u16;
typedef unsigned int u32;
typedef __attribute__((ext_vector_type(8))) short short8;
typedef __attribute__((ext_vector_type(4))) float float4v;

__device__ __forceinline__ float b2f(u16 u) {
    union { u32 i; float f; } v; v.i = ((u32)u) << 16; return v.f;
}
__device__ __forceinline__ u16 f2b(float f) {
    union { float f; u32 i; } v; v.f = f;
    u32 i = v.i;
    return (u16)((i + 0x7FFFu + ((i >> 16) & 1u)) >> 16);
}

// ---------------- detect int64 vs int32 edge_index encoding ----------------
__global__ void k_detect(const int* __restrict__ ei_raw, int* flag) {
    if (blockIdx.x == 0 && threadIdx.x == 0) {
        int z = 0;
        for (int i = 0; i < 256; i++) if (ei_raw[2 * i + 1] == 0) z++;
        *flag = (z >= 128) ? 1 : 0;
    }
}

// ---------------- convert edge_index & batch to int32 ----------------
__global__ void k_cvt(const int* __restrict__ ei_raw, const int* __restrict__ batch_raw,
                      const int* __restrict__ flag, int* __restrict__ src,
                      int* __restrict__ dst, int* __restrict__ batch32) {
    int i = blockIdx.x * blockDim.x + threadIdx.x;
    int w = *flag;
    if (i < NE) {
        if (w) { src[i] = ei_raw[2 * i]; dst[i] = ei_raw[2 * (NE + i)]; }
        else   { src[i] = ei_raw[i];     dst[i] = ei_raw[NE + i]; }
    }
    if (i < NN) batch32[i] = w ? batch_raw[2 * i] : batch_raw[i];
}

// ---------------- init ----------------
__global__ void k_init(int* cnt, int* startg, int* endg) {
    int i = blockIdx.x * blockDim.x + threadIdx.x;
    if (i < NN) cnt[i] = 0;
    if (i < NG) { startg[i] = 0x7fffffff; endg[i] = 0; }
}

// ---------------- histogram of dst ----------------
__global__ void k_hist(const int* __restrict__ dst, int* cnt) {
    int e = blockIdx.x * blockDim.x + threadIdx.x;
    if (e < NE) atomicAdd(&cnt[dst[e]], 1);
}

// ---------------- single-block exclusive scan over 50000 ints ----------------
__global__ void k_scan(int* cnt, int* off) {
    __shared__ int s[1024];
    int t = threadIdx.x;
    int base = t * 49;
    int local = 0;
    for (int i = 0; i < 49; i++) {
        int idx = base + i;
        if (idx < NN) local += cnt[idx];
    }
    s[t] = local; __syncthreads();
    for (int d = 1; d < 1024; d <<= 1) {
        int v = s[t];
        int a = (t >= d) ? s[t - d] : 0;
        __syncthreads();
        s[t] = v + a;
        __syncthreads();
    }
    int run = s[t] - local;  // exclusive prefix
    for (int i = 0; i < 49; i++) {
        int idx = base + i;
        if (idx < NN) {
            int c = cnt[idx];
            off[idx] = run;
            run += c;
            cnt[idx] = 0;   // reset for scatter cursor
            if (idx == NN - 1) off[NN] = run;
        }
    }
}

// ---------------- scatter edges into CSR-by-dst ----------------
__global__ void k_scatter(const int* __restrict__ src, const int* __restrict__ dst,
                          const float* __restrict__ eattr, const int* __restrict__ off,
                          int* cur, int* __restrict__ csr_src, float* __restrict__ csr_attr) {
    int e = blockIdx.x * blockDim.x + threadIdx.x;
    if (e >= NE) return;
    int d = dst[e];
    int p = atomicAdd(&cur[d], 1);
    int slot = off[d] + p;
    csr_src[slot] = src[e];
    csr_attr[2 * slot]     = eattr[2 * e];
    csr_attr[2 * slot + 1] = eattr[2 * e + 1];
}

// ---------------- x (f32) -> bf16 ----------------
__global__ void k_x2b(const float* __restrict__ x, u16* __restrict__ xb) {
    int i = blockIdx.x * blockDim.x + threadIdx.x;
    if (i < NN * 64) xb[i] = f2b(x[i]);
}

// ---------------- Gaussian weights for ONE layer, CSR order, fp32 ----------------
__global__ void k_gw(const float* __restrict__ csr_attr, const float* __restrict__ mu,
                     const float* __restrict__ sg, float* __restrict__ gw) {
    int j = blockIdx.x * blockDim.x + threadIdx.x;
    if (j >= NE) return;
    float a0 = csr_attr[2 * j], a1 = csr_attr[2 * j + 1];
    float o[4];
#pragma unroll
    for (int k = 0; k < 4; k++) {
        float d0 = a0 - mu[2 * k], d1 = a1 - mu[2 * k + 1];
        float s0 = sg[2 * k], s1 = sg[2 * k + 1];
        float t = d0 * d0 / (1e-15f + s0 * s0) + d1 * d1 / (1e-15f + s1 * s1);
        o[k] = expf(-0.5f * t);
    }
    *(float4*)(gw + (size_t)j * 4) = make_float4(o[0], o[1], o[2], o[3]);
}

// ---------------- pre-swizzle Wcat=[G2;rw] (f32) into bf16 MFMA B-fragment order ----------------
// bsw layout per layer: [(kt*4+ct)*64 + lane] 16B chunks; chunk elem j = Wcat[kt*32+(lane>>4)*8+j][ct*16+(lane&15)]
struct WParams { const float* g[4]; const float* rw[4]; };
__global__ void k_wprep(WParams P, u16* __restrict__ bsw) {
    int id = blockIdx.x * blockDim.x + threadIdx.x;
    if (id >= 4 * 20480) return;
    int l = id / 20480, r = id % 20480;
    int j = r & 7, lane = (r >> 3) & 63, ctkt = r >> 9;
    int ct = ctkt & 3, kt = ctkt >> 2;
    int k = kt * 32 + (lane >> 4) * 8 + j;
    int n = ct * 16 + (lane & 15);
    float v;
    if (k < 256) v = P.g[l][(k & 63) * 256 + (k >> 6) * 64 + n];  // G2[k][n] = g[d][kk*64+n]
    else         v = P.rw[l][(k - 256) * 64 + n];
    bsw[id] = f2b(v);
}

// ---------------- aggregation: y[n][k*64+d] = (1/deg) sum_e gw[e][k]*x[src][d] ----------------
__global__ __launch_bounds__(256) void k_agg(const u16* __restrict__ xin,
                                             const int* __restrict__ csr_src,
                                             const float4* __restrict__ gw,
                                             const int* __restrict__ off,
                                             u16* __restrict__ y) {
    int wid = (blockIdx.x * 256 + threadIdx.x) >> 6;  // node, one wave each
    int lane = threadIdx.x & 63;                       // feature d
    if (wid >= NN) return;
    int beg = off[wid], end = off[wid + 1];
    float a0 = 0.f, a1 = 0.f, a2 = 0.f, a3 = 0.f;
#pragma unroll 2
    for (int j = beg; j < end; j++) {
        int s = csr_src[j];
        float4 w = gw[j];
        float xv = b2f(xin[(size_t)s * 64 + lane]);
        a0 += w.x * xv; a1 += w.y * xv; a2 += w.z * xv; a3 += w.w * xv;
    }
    int deg = end - beg;
    float sc = 1.0f / (float)(deg > 1 ? deg : 1);
    size_t o = (size_t)wid * 256 + lane;
    y[o]       = f2b(a0 * sc);
    y[o + 64]  = f2b(a1 * sc);
    y[o + 128] = f2b(a2 * sc);
    y[o + 192] = f2b(a3 * sc);
}

// ---------------- GEMM: xout = lrelu([y|xin](N,320) @ Wcat(320,64) + b); opt x3 = x0 + xout ----------------
#define LDA 328  // 320 + 8 u16 pad -> rows 656B, 16B aligned
__global__ __launch_bounds__(256) void k_gemm(const u16* __restrict__ y,
                                              const u16* __restrict__ xin,
                                              const u16* __restrict__ bsw,
                                              const float* __restrict__ bias,
                                              u16* __restrict__ xout,
                                              const u16* __restrict__ xadd,
                                              u16* __restrict__ x3out) {
    __shared__ u16 As[64 * LDA];
    int t = threadIdx.x;
    int rbase = blockIdx.x * 64;
    // cooperative stage A = [y | xin] rows rbase..rbase+63 (2560 x 16B chunks)
#pragma unroll
    for (int c = 0; c < 10; c++) {
        int idx = t + c * 256;
        int row = idx / 40, pos = idx % 40;
        int grow = rbase + row;
        uint4 v = make_uint4(0, 0, 0, 0);
        if (grow < NN) {
            if (pos < 32) v = *(const uint4*)(y + (size_t)grow * 256 + pos * 8);
            else          v = *(const uint4*)(xin + (size_t)grow * 64 + (pos - 32) * 8);
        }
        *(uint4*)(&As[row * LDA + pos * 8]) = v;
    }
    __syncthreads();

    int wave = t >> 6, lane = t & 63, lr = lane & 15, lg = lane >> 4;
    float4v acc0 = {0.f,0.f,0.f,0.f}, acc1 = {0.f,0.f,0.f,0.f};
    float4v acc2 = {0.f,0.f,0.f,0.f}, acc3 = {0.f,0.f,0.f,0.f};
    const u16* ar = &As[(wave * 16 + lr) * LDA + lg * 8];
    const uint4* bp = (const uint4*)bsw;
    for (int kt = 0; kt < 10; kt++) {
        short8 a  = *(const short8*)(ar + kt * 32);
        short8 b0 = *(const short8*)(bp + (kt * 4 + 0) * 64 + lane);
        short8 b1 = *(const short8*)(bp + (kt * 4 + 1) * 64 + lane);
        short8 b2 = *(const short8*)(bp + (kt * 4 + 2) * 64 + lane);
        short8 b3 = *(const short8*)(bp + (kt * 4 + 3) * 64 + lane);
        acc0 = __builtin_amdgcn_mfma_f32_16x16x32_bf16(a, b0, acc0, 0, 0, 0);
        acc1 = __builtin_amdgcn_mfma_f32_16x16x32_bf16(a, b1, acc1, 0, 0, 0);
        acc2 = __builtin_amdgcn_mfma_f32_16x16x32_bf16(a, b2, acc2, 0, 0, 0);
        acc3 = __builtin_amdgcn_mfma_f32_16x16x32_bf16(a, b3, acc3, 0, 0, 0);
    }
    float4v accs[4] = {acc0, acc1, acc2, acc3};
#pragma unroll
    for (int ct = 0; ct < 4; ct++) {
        int col = ct * 16 + lr;
        float bv = bias[col];
#pragma unroll
        for (int reg = 0; reg < 4; reg++) {
            int grow = rbase + wave * 16 + lg * 4 + reg;  // C/D: row=(lane>>4)*4+reg, col=lane&15
            if (grow < NN) {
                float v = accs[ct][reg] + bv;
                v = v > 0.f ? v : 0.01f * v;
                xout[(size_t)grow * 64 + col] = f2b(v);
                if (x3out) {
                    float s2 = v + b2f(xadd[(size_t)grow * 64 + col]);
                    x3out[(size_t)grow * 64 + col] = f2b(s2);
                }
            }
        }
    }
}

// ---------------- per-graph node ranges: batch sorted -> boundary scan, no atomics ----------------
__global__ void k_bounds2(const int* __restrict__ batch, int* startg, int* endg) {
    int n = blockIdx.x * blockDim.x + threadIdx.x;
    if (n >= NN) return;
    int b = batch[n];
    if (n == 0) {
        startg[b] = 0;
    } else {
        int bp = batch[n - 1];
        if (bp != b) { startg[b] = n; endg[bp] = n; }
    }
    if (n == NN - 1) endg[b] = NN;
}

// ---------------- pool stage 1: partial max over node slice, concat [x4,x1,x2,x3] ----------------
__global__ __launch_bounds__(256) void k_pool1(const u16* __restrict__ x4, const u16* __restrict__ x1,
                                               const u16* __restrict__ x2, const u16* __restrict__ x3,
                                               const int* __restrict__ startg, const int* __restrict__ endg,
                                               float* __restrict__ partial) {
    int g = blockIdx.x, sl = blockIdx.y;
    int c = threadIdx.x;
    const u16* arr = (c < 64) ? x4 : (c < 128) ? x1 : (c < 192) ? x2 : x3;
    int h = c & 63;
    int s = startg[g], e = endg[g];
    int len = e - s;
    int chunk = (len + NSL - 1) / NSL;
    int s0 = s + sl * chunk;
    int e0 = s0 + chunk; if (e0 > e) e0 = e;
    float m = -3.4e38f;
    for (int n = s0; n < e0; n++) {
        float v = b2f(arr[(size_t)n * 64 + h]);
        m = v > m ? v : m;
    }
    partial[((size_t)g * NSL + sl) * 256 + c] = m;
}

// ---------------- pool stage 2: reduce slices ----------------
__global__ __launch_bounds__(256) void k_pool2(const float* __restrict__ partial,
                                               float* __restrict__ pooled) {
    int g = blockIdx.x, c = threadIdx.x;
    float m = -3.4e38f;
#pragma unroll
    for (int sl = 0; sl < NSL; sl++) {
        float v = partial[((size_t)g * NSL + sl) * 256 + c];
        m = v > m ? v : m;
    }
    pooled[g * 256 + c] = m;
}

// ---------------- final MLP: (50,256)@(256,64) -> BN -> relu -> (64,10), fp32 OUT ----------------
__global__ void k_final(const float* __restrict__ pooled, const float* __restrict__ w1,
                        const float* __restrict__ b1, const float* __restrict__ gamma,
                        const float* __restrict__ beta, const float* __restrict__ w2,
                        const float* __restrict__ b2v, float* __restrict__ out) {
    __shared__ float zsh[64];
    int g = blockIdx.x, h = threadIdx.x;
    float z = b1[h];
    const float* p = pooled + g * 256;
    for (int j = 0; j < 256; j++) z += p[j] * w1[j * 64 + h];
    z = z * 0.9999950000374997f * gamma[h] + beta[h];  // /sqrt(1+1e-5)
    z = z > 0.f ? z : 0.f;
    zsh[h] = z;
    __syncthreads();
    if (h < 10) {
        float o = b2v[h];
        for (int k = 0; k < 64; k++) o += zsh[k] * w2[k * 10 + h];
        out[g * 10 + h] = o;   // fp32 output
    }
}

extern "C" void kernel_launch(void* const* d_in, const int* in_sizes, int n_in,
                              void* d_out, int out_size, void* d_ws, size_t ws_size,
                              hipStream_t stream) {
    const float* x_in    = (const float*)d_in[0];
    const int* ei_raw    = (const int*)d_in[1];
    const int* batch_raw = (const int*)d_in[2];
    const float* eattr   = (const float*)d_in[3];

    const float *g_[4], *mu_[4], *sg_[4], *rw_[4], *b_[4];
    for (int i = 0; i < 4; i++) {
        g_[i]  = (const float*)d_in[4 + 5 * i + 0];
        mu_[i] = (const float*)d_in[4 + 5 * i + 1];
        sg_[i] = (const float*)d_in[4 + 5 * i + 2];
        rw_[i] = (const float*)d_in[4 + 5 * i + 3];
        b_[i]  = (const float*)d_in[4 + 5 * i + 4];
    }
    const float* w_mlp1 = (const float*)d_in[24];
    const float* b_mlp1 = (const float*)d_in[25];
    const float* bn_g   = (const float*)d_in[26];
    const float* bn_b   = (const float*)d_in[27];
    const float* w_mlp2 = (const float*)d_in[28];
    const float* b_mlp2 = (const float*)d_in[29];
    float* out = (float*)d_out;

    // workspace carve-up (~46 MB)
    char* ws = (char*)d_ws;
    size_t o = 0;
    auto take = [&](size_t bytes) { size_t r = o; o += (bytes + 255) & ~(size_t)255; return r; };
    int*   flag     = (int*)(ws + take(4));
    int*   src      = (int*)(ws + take((size_t)NE * 4));
    int*   dst      = (int*)(ws + take((size_t)NE * 4));
    int*   batch32  = (int*)(ws + take((size_t)NN * 4));
    int*   off      = (int*)(ws + take((NN + 1) * 4));
    int*   cnt      = (int*)(ws + take((size_t)NN * 4));
    int*   csr_src  = (int*)(ws + take((size_t)NE * 4));
    float* csr_attr = (float*)(ws + take((size_t)NE * 8));
    float* gw       = (float*)(ws + take((size_t)NE * 16));      // one layer at a time
    u16*   xb       = (u16*)(ws + take((size_t)NN * 64 * 2));
    u16*   y        = (u16*)(ws + take((size_t)NN * 256 * 2));
    u16*   x0       = (u16*)(ws + take((size_t)NN * 64 * 2));
    u16*   x1       = (u16*)(ws + take((size_t)NN * 64 * 2));
    u16*   x2       = (u16*)(ws + take((size_t)NN * 64 * 2));
    u16*   x3       = (u16*)(ws + take((size_t)NN * 64 * 2));
    u16*   x4       = (u16*)(ws + take((size_t)NN * 64 * 2));
    u16*   bsw      = (u16*)(ws + take((size_t)4 * 320 * 64 * 2));
    float* partial  = (float*)(ws + take((size_t)NG * NSL * 256 * 4));
    float* pooled   = (float*)(ws + take((size_t)NG * 256 * 4));
    int*   startg   = (int*)(ws + take(NG * 4));
    int*   endg     = (int*)(ws + take(NG * 4));
    (void)ws_size; (void)in_sizes; (void)n_in; (void)out_size;

    // index dtype normalization
    k_detect<<<dim3(1), dim3(64), 0, stream>>>(ei_raw, flag);
    k_cvt<<<dim3((NE + 255) / 256), dim3(256), 0, stream>>>(ei_raw, batch_raw, flag, src, dst, batch32);

    // CSR build
    k_init<<<dim3((NN + 255) / 256), dim3(256), 0, stream>>>(cnt, startg, endg);
    k_hist<<<dim3(NE / 256), dim3(256), 0, stream>>>(dst, cnt);
    k_scan<<<dim3(1), dim3(1024), 0, stream>>>(cnt, off);
    k_scatter<<<dim3(NE / 256), dim3(256), 0, stream>>>(src, dst, eattr, off, cnt, csr_src, csr_attr);
    k_x2b<<<dim3((NN * 64 + 255) / 256), dim3(256), 0, stream>>>(x_in, xb);

    WParams WP;
    for (int i = 0; i < 4; i++) { WP.g[i] = g_[i]; WP.rw[i] = rw_[i]; }
    k_wprep<<<dim3(4 * 20480 / 256), dim3(256), 0, stream>>>(WP, bsw);

    const int aggGrid = NN / 4;            // 4 waves (nodes) per 256-thr block
    const int gemmGrid = (NN + 63) / 64;   // 64 rows per block

    const u16* lin[4]  = {xb, x0, x1, x3};
    u16*       lout[4] = {x0, x1, x2, x4};
    for (int l = 0; l < 4; l++) {
        k_gw<<<dim3(NE / 256), dim3(256), 0, stream>>>(csr_attr, mu_[l], sg_[l], gw);
        k_agg<<<dim3(aggGrid), dim3(256), 0, stream>>>(
            lin[l], csr_src, (const float4*)gw, off, y);
        k_gemm<<<dim3(gemmGrid), dim3(256), 0, stream>>>(
            y, lin[l], bsw + (size_t)l * 20480, b_[l], lout[l],
            (l == 2) ? x0 : (const u16*)nullptr,
            (l == 2) ? x3 : (u16*)nullptr);
    }

    k_bounds2<<<dim3((NN + 255) / 256), dim3(256), 0, stream>>>(batch32, startg, endg);
    k_pool1<<<dim3(NG, NSL), dim3(256), 0, stream>>>(x4, x1, x2, x3, startg, endg, partial);
    k_pool2<<<dim3(NG), dim3(256), 0, stream>>>(partial, pooled);
    k_final<<<dim3(NG), dim3(64), 0, stream>>>(pooled, w_mlp1, b_mlp1, bn_g, bn_b, w_mlp2, b_mlp2, out);
}

// Round 9
// 592.699 us; speedup vs baseline: 3.5023x; 1.1993x over previous
//
#include <hip/hip_runtime.h>
#include <hip/hip_bf16.h>

#define NN 50000
#define NE 800000
#define NG 50
#define NSL 16    // pool slices per graph
#define NSCB 196  // scan blocks (196*256 = 50176 >= NN+1)

typedef unsigned short u16;
typedef unsigned int u32;
typedef __attribute__((ext_vector_type(8))) short short8;
typedef __attribute__((ext_vector_type(4))) float float4v;

__device__ __forceinline__ float b2f(u16 u) {
    union { u32 i; float f; } v; v.i = ((u32)u) << 16; return v.f;
}
__device__ __forceinline__ u16 f2b(float f) {
    union { float f; u32 i; } v; v.f = f;
    u32 i = v.i;
    return (u16)((i + 0x7FFFu + ((i >> 16) & 1u)) >> 16);
}

// ---------------- detect int64 vs int32 edge_index encoding (parallel) ----------------
__global__ void k_detect(const int* __restrict__ ei_raw, int* flag) {
    __shared__ int cs[256];
    int t = threadIdx.x;
    cs[t] = (ei_raw[2 * t + 1] == 0) ? 1 : 0;
    __syncthreads();
    for (int d = 128; d > 0; d >>= 1) {
        if (t < d) cs[t] += cs[t + d];
        __syncthreads();
    }
    if (t == 0) *flag = (cs[0] >= 128) ? 1 : 0;
}

// ---------------- convert edge_index & batch to int32 ----------------
__global__ void k_cvt(const int* __restrict__ ei_raw, const int* __restrict__ batch_raw,
                      const int* __restrict__ flag, int* __restrict__ src,
                      int* __restrict__ dst, int* __restrict__ batch32) {
    int i = blockIdx.x * blockDim.x + threadIdx.x;
    int w = *flag;
    if (i < NE) {
        if (w) { src[i] = ei_raw[2 * i]; dst[i] = ei_raw[2 * (NE + i)]; }
        else   { src[i] = ei_raw[i];     dst[i] = ei_raw[NE + i]; }
    }
    if (i < NN) batch32[i] = w ? batch_raw[2 * i] : batch_raw[i];
}

// ---------------- init ----------------
__global__ void k_init(int* cnt, int* startg, int* endg) {
    int i = blockIdx.x * blockDim.x + threadIdx.x;
    if (i < NN) cnt[i] = 0;
    if (i < NG) { startg[i] = 0x7fffffff; endg[i] = 0; }
}

// ---------------- histogram of dst ----------------
__global__ void k_hist(const int* __restrict__ dst, int* cnt) {
    int e = blockIdx.x * blockDim.x + threadIdx.x;
    if (e < NE) atomicAdd(&cnt[dst[e]], 1);
}

// ---------------- scan stage A: block-local exclusive scan + block sums; zero cnt ----------------
__global__ __launch_bounds__(256) void k_scanA(int* __restrict__ cnt, int* __restrict__ excl,
                                               int* __restrict__ bsum) {
    __shared__ int s[256];
    int t = threadIdx.x, b = blockIdx.x;
    int i = b * 256 + t;
    int v = (i < NN) ? cnt[i] : 0;
    s[t] = v; __syncthreads();
    for (int d = 1; d < 256; d <<= 1) {
        int x = s[t];
        int y = (t >= d) ? s[t - d] : 0;
        __syncthreads();
        s[t] = x + y;
        __syncthreads();
    }
    excl[i] = s[t] - v;               // exclusive prefix within block
    if (t == 255) bsum[b] = s[255];   // block total
    if (i < NN) cnt[i] = 0;           // reset for scatter cursor
}

// ---------------- scan stage B: exclusive scan of block sums ----------------
__global__ __launch_bounds__(256) void k_scanB(const int* __restrict__ bsum, int* __restrict__ ebsum) {
    __shared__ int s[256];
    int t = threadIdx.x;
    int v = (t < NSCB) ? bsum[t] : 0;
    s[t] = v; __syncthreads();
    for (int d = 1; d < 256; d <<= 1) {
        int x = s[t];
        int y = (t >= d) ? s[t - d] : 0;
        __syncthreads();
        s[t] = x + y;
        __syncthreads();
    }
    ebsum[t] = s[t] - v;
}

// ---------------- scan stage C: combine ----------------
__global__ void k_scanC(const int* __restrict__ excl, const int* __restrict__ ebsum,
                        int* __restrict__ off) {
    int i = blockIdx.x * blockDim.x + threadIdx.x;
    if (i <= NN) off[i] = excl[i] + ebsum[i >> 8];
}

// ---------------- scatter edges into CSR-by-dst ----------------
__global__ void k_scatter(const int* __restrict__ src, const int* __restrict__ dst,
                          const float* __restrict__ eattr, const int* __restrict__ off,
                          int* cur, int* __restrict__ csr_src, float* __restrict__ csr_attr) {
    int e = blockIdx.x * blockDim.x + threadIdx.x;
    if (e >= NE) return;
    int d = dst[e];
    int p = atomicAdd(&cur[d], 1);
    int slot = off[d] + p;
    csr_src[slot] = src[e];
    csr_attr[2 * slot]     = eattr[2 * e];
    csr_attr[2 * slot + 1] = eattr[2 * e + 1];
}

// ---------------- x (f32) -> bf16 ----------------
__global__ void k_x2b(const float* __restrict__ x, u16* __restrict__ xb) {
    int i = blockIdx.x * blockDim.x + threadIdx.x;
    if (i < NN * 64) xb[i] = f2b(x[i]);
}

// ---------------- Gaussian weights for ONE layer, CSR order, fp32 ----------------
__global__ void k_gw(const float* __restrict__ csr_attr, const float* __restrict__ mu,
                     const float* __restrict__ sg, float* __restrict__ gw) {
    int j = blockIdx.x * blockDim.x + threadIdx.x;
    if (j >= NE) return;
    float a0 = csr_attr[2 * j], a1 = csr_attr[2 * j + 1];
    float o[4];
#pragma unroll
    for (int k = 0; k < 4; k++) {
        float d0 = a0 - mu[2 * k], d1 = a1 - mu[2 * k + 1];
        float s0 = sg[2 * k], s1 = sg[2 * k + 1];
        float t = d0 * d0 / (1e-15f + s0 * s0) + d1 * d1 / (1e-15f + s1 * s1);
        o[k] = expf(-0.5f * t);
    }
    *(float4*)(gw + (size_t)j * 4) = make_float4(o[0], o[1], o[2], o[3]);
}

// ---------------- pre-swizzle Wcat=[G2;rw] (f32) into bf16 MFMA B-fragment order ----------------
struct WParams { const float* g[4]; const float* rw[4]; };
__global__ void k_wprep(WParams P, u16* __restrict__ bsw) {
    int id = blockIdx.x * blockDim.x + threadIdx.x;
    if (id >= 4 * 20480) return;
    int l = id / 20480, r = id % 20480;
    int j = r & 7, lane = (r >> 3) & 63, ctkt = r >> 9;
    int ct = ctkt & 3, kt = ctkt >> 2;
    int k = kt * 32 + (lane >> 4) * 8 + j;
    int n = ct * 16 + (lane & 15);
    float v;
    if (k < 256) v = P.g[l][(k & 63) * 256 + (k >> 6) * 64 + n];  // G2[k][n] = g[d][kk*64+n]
    else         v = P.rw[l][(k - 256) * 64 + n];
    bsw[id] = f2b(v);
}

// ---------------- aggregation: y[n][k*64+d] = (1/deg) sum_e gw[e][k]*x[src][d] ----------------
__global__ __launch_bounds__(256) void k_agg(const u16* __restrict__ xin,
                                             const int* __restrict__ csr_src,
                                             const float4* __restrict__ gw,
                                             const int* __restrict__ off,
                                             u16* __restrict__ y) {
    int wid = (blockIdx.x * 256 + threadIdx.x) >> 6;  // node, one wave each
    int lane = threadIdx.x & 63;                       // feature d
    if (wid >= NN) return;
    int beg = off[wid], end = off[wid + 1];
    float a0 = 0.f, a1 = 0.f, a2 = 0.f, a3 = 0.f;
#pragma unroll 2
    for (int j = beg; j < end; j++) {
        int s = csr_src[j];
        float4 w = gw[j];
        float xv = b2f(xin[(size_t)s * 64 + lane]);
        a0 += w.x * xv; a1 += w.y * xv; a2 += w.z * xv; a3 += w.w * xv;
    }
    int deg = end - beg;
    float sc = 1.0f / (float)(deg > 1 ? deg : 1);
    size_t o = (size_t)wid * 256 + lane;
    y[o]       = f2b(a0 * sc);
    y[o + 64]  = f2b(a1 * sc);
    y[o + 128] = f2b(a2 * sc);
    y[o + 192] = f2b(a3 * sc);
}

// ---------------- GEMM: xout = lrelu([y|xin](N,320) @ Wcat(320,64) + b); opt x3 = x0 + xout ----------------
#define LDA 328  // 320 + 8 u16 pad -> rows 656B, 16B aligned
__global__ __launch_bounds__(256) void k_gemm(const u16* __restrict__ y,
                                              const u16* __restrict__ xin,
                                              const u16* __restrict__ bsw,
                                              const float* __restrict__ bias,
                                              u16* __restrict__ xout,
                                              const u16* __restrict__ xadd,
                                              u16* __restrict__ x3out) {
    __shared__ u16 As[64 * LDA];
    int t = threadIdx.x;
    int rbase = blockIdx.x * 64;
#pragma unroll
    for (int c = 0; c < 10; c++) {
        int idx = t + c * 256;
        int row = idx / 40, pos = idx % 40;
        int grow = rbase + row;
        uint4 v = make_uint4(0, 0, 0, 0);
        if (grow < NN) {
            if (pos < 32) v = *(const uint4*)(y + (size_t)grow * 256 + pos * 8);
            else          v = *(const uint4*)(xin + (size_t)grow * 64 + (pos - 32) * 8);
        }
        *(uint4*)(&As[row * LDA + pos * 8]) = v;
    }
    __syncthreads();

    int wave = t >> 6, lane = t & 63, lr = lane & 15, lg = lane >> 4;
    float4v acc0 = {0.f,0.f,0.f,0.f}, acc1 = {0.f,0.f,0.f,0.f};
    float4v acc2 = {0.f,0.f,0.f,0.f}, acc3 = {0.f,0.f,0.f,0.f};
    const u16* ar = &As[(wave * 16 + lr) * LDA + lg * 8];
    const uint4* bp = (const uint4*)bsw;
    for (int kt = 0; kt < 10; kt++) {
        short8 a  = *(const short8*)(ar + kt * 32);
        short8 b0 = *(const short8*)(bp + (kt * 4 + 0) * 64 + lane);
        short8 b1 = *(const short8*)(bp + (kt * 4 + 1) * 64 + lane);
        short8 b2 = *(const short8*)(bp + (kt * 4 + 2) * 64 + lane);
        short8 b3 = *(const short8*)(bp + (kt * 4 + 3) * 64 + lane);
        acc0 = __builtin_amdgcn_mfma_f32_16x16x32_bf16(a, b0, acc0, 0, 0, 0);
        acc1 = __builtin_amdgcn_mfma_f32_16x16x32_bf16(a, b1, acc1, 0, 0, 0);
        acc2 = __builtin_amdgcn_mfma_f32_16x16x32_bf16(a, b2, acc2, 0, 0, 0);
        acc3 = __builtin_amdgcn_mfma_f32_16x16x32_bf16(a, b3, acc3, 0, 0, 0);
    }
    float4v accs[4] = {acc0, acc1, acc2, acc3};
#pragma unroll
    for (int ct = 0; ct < 4; ct++) {
        int col = ct * 16 + lr;
        float bv = bias[col];
#pragma unroll
        for (int reg = 0; reg < 4; reg++) {
            int grow = rbase + wave * 16 + lg * 4 + reg;  // C/D: row=(lane>>4)*4+reg, col=lane&15
            if (grow < NN) {
                float v = accs[ct][reg] + bv;
                v = v > 0.f ? v : 0.01f * v;
                xout[(size_t)grow * 64 + col] = f2b(v);
                if (x3out) {
                    float s2 = v + b2f(xadd[(size_t)grow * 64 + col]);
                    x3out[(size_t)grow * 64 + col] = f2b(s2);
                }
            }
        }
    }
}

// ---------------- per-graph node ranges: batch sorted -> boundary scan, no atomics ----------------
__global__ void k_bounds2(const int* __restrict__ batch, int* startg, int* endg) {
    int n = blockIdx.x * blockDim.x + threadIdx.x;
    if (n >= NN) return;
    int b = batch[n];
    if (n == 0) {
        startg[b] = 0;
    } else {
        int bp = batch[n - 1];
        if (bp != b) { startg[b] = n; endg[bp] = n; }
    }
    if (n == NN - 1) endg[b] = NN;
}

// ---------------- pool stage 1: partial max over node slice, concat [x4,x1,x2,x3] ----------------
__global__ __launch_bounds__(256) void k_pool1(const u16* __restrict__ x4, const u16* __restrict__ x1,
                                               const u16* __restrict__ x2, const u16* __restrict__ x3,
                                               const int* __restrict__ startg, const int* __restrict__ endg,
                                               float* __restrict__ partial) {
    int g = blockIdx.x, sl = blockIdx.y;
    int c = threadIdx.x;
    const u16* arr = (c < 64) ? x4 : (c < 128) ? x1 : (c < 192) ? x2 : x3;
    int h = c & 63;
    int s = startg[g], e = endg[g];
    int len = e - s;
    int chunk = (len + NSL - 1) / NSL;
    int s0 = s + sl * chunk;
    int e0 = s0 + chunk; if (e0 > e) e0 = e;
    float m = -3.4e38f;
    for (int n = s0; n < e0; n++) {
        float v = b2f(arr[(size_t)n * 64 + h]);
        m = v > m ? v : m;
    }
    partial[((size_t)g * NSL + sl) * 256 + c] = m;
}

// ---------------- pool stage 2: reduce slices ----------------
__global__ __launch_bounds__(256) void k_pool2(const float* __restrict__ partial,
                                               float* __restrict__ pooled) {
    int g = blockIdx.x, c = threadIdx.x;
    float m = -3.4e38f;
#pragma unroll
    for (int sl = 0; sl < NSL; sl++) {
        float v = partial[((size_t)g * NSL + sl) * 256 + c];
        m = v > m ? v : m;
    }
    pooled[g * 256 + c] = m;
}

// ---------------- final MLP: (50,256)@(256,64) -> BN -> relu -> (64,10), fp32 OUT ----------------
__global__ void k_final(const float* __restrict__ pooled, const float* __restrict__ w1,
                        const float* __restrict__ b1, const float* __restrict__ gamma,
                        const float* __restrict__ beta, const float* __restrict__ w2,
                        const float* __restrict__ b2v, float* __restrict__ out) {
    __shared__ float zsh[64];
    int g = blockIdx.x, h = threadIdx.x;
    float z = b1[h];
    const float* p = pooled + g * 256;
    for (int j = 0; j < 256; j++) z += p[j] * w1[j * 64 + h];
    z = z * 0.9999950000374997f * gamma[h] + beta[h];  // /sqrt(1+1e-5)
    z = z > 0.f ? z : 0.f;
    zsh[h] = z;
    __syncthreads();
    if (h < 10) {
        float o = b2v[h];
        for (int k = 0; k < 64; k++) o += zsh[k] * w2[k * 10 + h];
        out[g * 10 + h] = o;   // fp32 output
    }
}

extern "C" void kernel_launch(void* const* d_in, const int* in_sizes, int n_in,
                              void* d_out, int out_size, void* d_ws, size_t ws_size,
                              hipStream_t stream) {
    const float* x_in    = (const float*)d_in[0];
    const int* ei_raw    = (const int*)d_in[1];
    const int* batch_raw = (const int*)d_in[2];
    const float* eattr   = (const float*)d_in[3];

    const float *g_[4], *mu_[4], *sg_[4], *rw_[4], *b_[4];
    for (int i = 0; i < 4; i++) {
        g_[i]  = (const float*)d_in[4 + 5 * i + 0];
        mu_[i] = (const float*)d_in[4 + 5 * i + 1];
        sg_[i] = (const float*)d_in[4 + 5 * i + 2];
        rw_[i] = (const float*)d_in[4 + 5 * i + 3];
        b_[i]  = (const float*)d_in[4 + 5 * i + 4];
    }
    const float* w_mlp1 = (const float*)d_in[24];
    const float* b_mlp1 = (const float*)d_in[25];
    const float* bn_g   = (const float*)d_in[26];
    const float* bn_b   = (const float*)d_in[27];
    const float* w_mlp2 = (const float*)d_in[28];
    const float* b_mlp2 = (const float*)d_in[29];
    float* out = (float*)d_out;

    // workspace carve-up (~46 MB)
    char* ws = (char*)d_ws;
    size_t o = 0;
    auto take = [&](size_t bytes) { size_t r = o; o += (bytes + 255) & ~(size_t)255; return r; };
    int*   flag     = (int*)(ws + take(4));
    int*   src      = (int*)(ws + take((size_t)NE * 4));
    int*   dst      = (int*)(ws + take((size_t)NE * 4));
    int*   batch32  = (int*)(ws + take((size_t)NN * 4));
    int*   off      = (int*)(ws + take((NN + 1) * 4));
    int*   cnt      = (int*)(ws + take((size_t)NN * 4));
    int*   excl     = (int*)(ws + take((size_t)NSCB * 256 * 4));
    int*   bsum     = (int*)(ws + take((size_t)NSCB * 4));
    int*   ebsum    = (int*)(ws + take(256 * 4));
    int*   csr_src  = (int*)(ws + take((size_t)NE * 4));
    float* csr_attr = (float*)(ws + take((size_t)NE * 8));
    float* gw       = (float*)(ws + take((size_t)NE * 16));      // one layer at a time
    u16*   xb       = (u16*)(ws + take((size_t)NN * 64 * 2));
    u16*   y        = (u16*)(ws + take((size_t)NN * 256 * 2));
    u16*   x0       = (u16*)(ws + take((size_t)NN * 64 * 2));
    u16*   x1       = (u16*)(ws + take((size_t)NN * 64 * 2));
    u16*   x2       = (u16*)(ws + take((size_t)NN * 64 * 2));
    u16*   x3       = (u16*)(ws + take((size_t)NN * 64 * 2));
    u16*   x4       = (u16*)(ws + take((size_t)NN * 64 * 2));
    u16*   bsw      = (u16*)(ws + take((size_t)4 * 320 * 64 * 2));
    float* partial  = (float*)(ws + take((size_t)NG * NSL * 256 * 4));
    float* pooled   = (float*)(ws + take((size_t)NG * 256 * 4));
    int*   startg   = (int*)(ws + take(NG * 4));
    int*   endg     = (int*)(ws + take(NG * 4));
    (void)ws_size; (void)in_sizes; (void)n_in; (void)out_size;

    // index dtype normalization
    k_detect<<<dim3(1), dim3(256), 0, stream>>>(ei_raw, flag);
    k_cvt<<<dim3((NE + 255) / 256), dim3(256), 0, stream>>>(ei_raw, batch_raw, flag, src, dst, batch32);

    // CSR build (parallel scan)
    k_init<<<dim3((NN + 255) / 256), dim3(256), 0, stream>>>(cnt, startg, endg);
    k_hist<<<dim3(NE / 256), dim3(256), 0, stream>>>(dst, cnt);
    k_scanA<<<dim3(NSCB), dim3(256), 0, stream>>>(cnt, excl, bsum);
    k_scanB<<<dim3(1), dim3(256), 0, stream>>>(bsum, ebsum);
    k_scanC<<<dim3(NSCB), dim3(256), 0, stream>>>(excl, ebsum, off);
    k_scatter<<<dim3(NE / 256), dim3(256), 0, stream>>>(src, dst, eattr, off, cnt, csr_src, csr_attr);
    k_x2b<<<dim3((NN * 64 + 255) / 256), dim3(256), 0, stream>>>(x_in, xb);

    WParams WP;
    for (int i = 0; i < 4; i++) { WP.g[i] = g_[i]; WP.rw[i] = rw_[i]; }
    k_wprep<<<dim3(4 * 20480 / 256), dim3(256), 0, stream>>>(WP, bsw);

    const int aggGrid = NN / 4;            // 4 waves (nodes) per 256-thr block
    const int gemmGrid = (NN + 63) / 64;   // 64 rows per block

    const u16* lin[4]  = {xb, x0, x1, x3};
    u16*       lout[4] = {x0, x1, x2, x4};
    for (int l = 0; l < 4; l++) {
        k_gw<<<dim3(NE / 256), dim3(256), 0, stream>>>(csr_attr, mu_[l], sg_[l], gw);
        k_agg<<<dim3(aggGrid), dim3(256), 0, stream>>>(
            lin[l], csr_src, (const float4*)gw, off, y);
        k_gemm<<<dim3(gemmGrid), dim3(256), 0, stream>>>(
            y, lin[l], bsw + (size_t)l * 20480, b_[l], lout[l],
            (l == 2) ? x0 : (const u16*)nullptr,
            (l == 2) ? x3 : (u16*)nullptr);
    }

    k_bounds2<<<dim3((NN + 255) / 256), dim3(256), 0, stream>>>(batch32, startg, endg);
    k_pool1<<<dim3(NG, NSL), dim3(256), 0, stream>>>(x4, x1, x2, x3, startg, endg, partial);
    k_pool2<<<dim3(NG), dim3(256), 0, stream>>>(partial, pooled);
    k_final<<<dim3(NG), dim3(64), 0, stream>>>(pooled, w_mlp1, b_mlp1, bn_g, bn_b, w_mlp2, b_mlp2, out);
}

// Round 10
// 568.237 us; speedup vs baseline: 3.6531x; 1.0430x over previous
//
#include <hip/hip_runtime.h>
#include <hip/hip_bf16.h>

#define NN 50000
#define NE 800000
#define NG 50
#define NSL 16    // pool slices per graph
#define NSCB 196  // scan blocks (196*256 = 50176 >= NN+1)

typedef unsigned short u16;
typedef unsigned int u32;
typedef __attribute__((ext_vector_type(8))) short short8;
typedef __attribute__((ext_vector_type(4))) float float4v;

__device__ __forceinline__ float b2f(u16 u) {
    union { u32 i; float f; } v; v.i = ((u32)u) << 16; return v.f;
}
__device__ __forceinline__ u16 f2b(float f) {
    union { float f; u32 i; } v; v.f = f;
    u32 i = v.i;
    return (u16)((i + 0x7FFFu + ((i >> 16) & 1u)) >> 16);
}

// ---------------- detect int64 vs int32 edge_index encoding (parallel) ----------------
__global__ void k_detect(const int* __restrict__ ei_raw, int* flag) {
    __shared__ int cs[256];
    int t = threadIdx.x;
    cs[t] = (ei_raw[2 * t + 1] == 0) ? 1 : 0;
    __syncthreads();
    for (int d = 128; d > 0; d >>= 1) {
        if (t < d) cs[t] += cs[t + d];
        __syncthreads();
    }
    if (t == 0) *flag = (cs[0] >= 128) ? 1 : 0;
}

// ---------------- convert edge_index & batch to int32 ----------------
__global__ void k_cvt(const int* __restrict__ ei_raw, const int* __restrict__ batch_raw,
                      const int* __restrict__ flag, int* __restrict__ src,
                      int* __restrict__ dst, int* __restrict__ batch32) {
    int i = blockIdx.x * blockDim.x + threadIdx.x;
    int w = *flag;
    if (i < NE) {
        if (w) { src[i] = ei_raw[2 * i]; dst[i] = ei_raw[2 * (NE + i)]; }
        else   { src[i] = ei_raw[i];     dst[i] = ei_raw[NE + i]; }
    }
    if (i < NN) batch32[i] = w ? batch_raw[2 * i] : batch_raw[i];
}

// ---------------- init ----------------
__global__ void k_init(int* cnt, int* startg, int* endg) {
    int i = blockIdx.x * blockDim.x + threadIdx.x;
    if (i < NN) cnt[i] = 0;
    if (i < NG) { startg[i] = 0x7fffffff; endg[i] = 0; }
}

// ---------------- histogram of dst ----------------
__global__ void k_hist(const int* __restrict__ dst, int* cnt) {
    int e = blockIdx.x * blockDim.x + threadIdx.x;
    if (e < NE) atomicAdd(&cnt[dst[e]], 1);
}

// ---------------- scan stage A: block-local exclusive scan + block sums; zero cnt ----------------
__global__ __launch_bounds__(256) void k_scanA(int* __restrict__ cnt, int* __restrict__ excl,
                                               int* __restrict__ bsum) {
    __shared__ int s[256];
    int t = threadIdx.x, b = blockIdx.x;
    int i = b * 256 + t;
    int v = (i < NN) ? cnt[i] : 0;
    s[t] = v; __syncthreads();
    for (int d = 1; d < 256; d <<= 1) {
        int x = s[t];
        int y = (t >= d) ? s[t - d] : 0;
        __syncthreads();
        s[t] = x + y;
        __syncthreads();
    }
    excl[i] = s[t] - v;               // exclusive prefix within block
    if (t == 255) bsum[b] = s[255];   // block total
    if (i < NN) cnt[i] = 0;           // reset for scatter cursor
}

// ---------------- scan stage B: exclusive scan of block sums ----------------
__global__ __launch_bounds__(256) void k_scanB(const int* __restrict__ bsum, int* __restrict__ ebsum) {
    __shared__ int s[256];
    int t = threadIdx.x;
    int v = (t < NSCB) ? bsum[t] : 0;
    s[t] = v; __syncthreads();
    for (int d = 1; d < 256; d <<= 1) {
        int x = s[t];
        int y = (t >= d) ? s[t - d] : 0;
        __syncthreads();
        s[t] = x + y;
        __syncthreads();
    }
    ebsum[t] = s[t] - v;
}

// ---------------- scan stage C: combine ----------------
__global__ void k_scanC(const int* __restrict__ excl, const int* __restrict__ ebsum,
                        int* __restrict__ off) {
    int i = blockIdx.x * blockDim.x + threadIdx.x;
    if (i <= NN) off[i] = excl[i] + ebsum[i >> 8];
}

// ---------------- scatter edges into CSR-by-dst, ONE 16B record per edge ----------------
__global__ void k_scatter(const int* __restrict__ src, const int* __restrict__ dst,
                          const float* __restrict__ eattr, const int* __restrict__ off,
                          int* cur, uint4* __restrict__ rec) {
    int e = blockIdx.x * blockDim.x + threadIdx.x;
    if (e >= NE) return;
    int d = dst[e];
    int p = atomicAdd(&cur[d], 1);
    int slot = off[d] + p;
    uint4 r;
    r.x = (u32)src[e];
    r.y = __float_as_uint(eattr[2 * e]);
    r.z = __float_as_uint(eattr[2 * e + 1]);
    r.w = 0;
    rec[slot] = r;
}

// ---------------- x (f32) -> bf16 ----------------
__global__ void k_x2b(const float* __restrict__ x, u16* __restrict__ xb) {
    int i = blockIdx.x * blockDim.x + threadIdx.x;
    if (i < NN * 64) xb[i] = f2b(x[i]);
}

// ---------------- gw pack: all 4 layers in one pass; per layer {src, gw01, gw23, 0} 16B ----------------
struct GwParams { const float* mu[4]; const float* sg[4]; };
__global__ __launch_bounds__(256) void k_gwpack(const uint4* __restrict__ rec, GwParams P,
                                                uint4* __restrict__ arec) {
    int j = blockIdx.x * blockDim.x + threadIdx.x;
    if (j >= NE) return;
    uint4 r = rec[j];
    float a0 = __uint_as_float(r.y), a1 = __uint_as_float(r.z);
#pragma unroll
    for (int l = 0; l < 4; l++) {
        u32 p01, p23;
        {
            u16 w[4];
#pragma unroll
            for (int k = 0; k < 4; k++) {
                float d0 = a0 - P.mu[l][2 * k], d1 = a1 - P.mu[l][2 * k + 1];
                float s0 = P.sg[l][2 * k], s1 = P.sg[l][2 * k + 1];
                float t = d0 * d0 / (1e-15f + s0 * s0) + d1 * d1 / (1e-15f + s1 * s1);
                w[k] = f2b(expf(-0.5f * t));
            }
            p01 = (u32)w[0] | ((u32)w[1] << 16);
            p23 = (u32)w[2] | ((u32)w[3] << 16);
        }
        uint4 o; o.x = r.x; o.y = p01; o.z = p23; o.w = 0;
        arec[(size_t)l * NE + j] = o;
    }
}

// ---------------- pre-swizzle Wcat=[G2;rw] (f32) into bf16 MFMA B-fragment order ----------------
struct WParams { const float* g[4]; const float* rw[4]; };
__global__ void k_wprep(WParams P, u16* __restrict__ bsw) {
    int id = blockIdx.x * blockDim.x + threadIdx.x;
    if (id >= 4 * 20480) return;
    int l = id / 20480, r = id % 20480;
    int j = r & 7, lane = (r >> 3) & 63, ctkt = r >> 9;
    int ct = ctkt & 3, kt = ctkt >> 2;
    int k = kt * 32 + (lane >> 4) * 8 + j;
    int n = ct * 16 + (lane & 15);
    float v;
    if (k < 256) v = P.g[l][(k & 63) * 256 + (k >> 6) * 64 + n];  // G2[k][n] = g[d][kk*64+n]
    else         v = P.rw[l][(k - 256) * 64 + n];
    bsw[id] = f2b(v);
}

// ---------------- aggregation: y[n][k*64+d] = (1/deg) sum_e gw[e][k]*x[src][d] ----------------
__global__ __launch_bounds__(256) void k_agg(const u16* __restrict__ xin,
                                             const uint4* __restrict__ arec,
                                             const int* __restrict__ off,
                                             u16* __restrict__ y) {
    int wid = (blockIdx.x * 256 + threadIdx.x) >> 6;  // node, one wave each
    int lane = threadIdx.x & 63;                       // feature d
    if (wid >= NN) return;
    int beg = off[wid], end = off[wid + 1];
    float a0 = 0.f, a1 = 0.f, a2 = 0.f, a3 = 0.f;
#pragma unroll 2
    for (int j = beg; j < end; j++) {
        uint4 r = arec[j];                              // broadcast 16B
        float xv = b2f(xin[(size_t)r.x * 64 + lane]);
        a0 += b2f((u16)(r.y & 0xffffu)) * xv;
        a1 += b2f((u16)(r.y >> 16)) * xv;
        a2 += b2f((u16)(r.z & 0xffffu)) * xv;
        a3 += b2f((u16)(r.z >> 16)) * xv;
    }
    int deg = end - beg;
    float sc = 1.0f / (float)(deg > 1 ? deg : 1);
    size_t o = (size_t)wid * 256 + lane;
    y[o]       = f2b(a0 * sc);
    y[o + 64]  = f2b(a1 * sc);
    y[o + 128] = f2b(a2 * sc);
    y[o + 192] = f2b(a3 * sc);
}

// ---------------- GEMM: xout = lrelu([y|xin](N,320) @ Wcat(320,64) + b); opt x3 = x0 + xout ----------------
#define LDA 328  // 320 + 8 u16 pad -> rows 656B, 16B aligned
__global__ __launch_bounds__(256) void k_gemm(const u16* __restrict__ y,
                                              const u16* __restrict__ xin,
                                              const u16* __restrict__ bsw,
                                              const float* __restrict__ bias,
                                              u16* __restrict__ xout,
                                              const u16* __restrict__ xadd,
                                              u16* __restrict__ x3out) {
    __shared__ u16 As[64 * LDA];
    int t = threadIdx.x;
    int rbase = blockIdx.x * 64;
#pragma unroll
    for (int c = 0; c < 10; c++) {
        int idx = t + c * 256;
        int row = idx / 40, pos = idx % 40;
        int grow = rbase + row;
        uint4 v = make_uint4(0, 0, 0, 0);
        if (grow < NN) {
            if (pos < 32) v = *(const uint4*)(y + (size_t)grow * 256 + pos * 8);
            else          v = *(const uint4*)(xin + (size_t)grow * 64 + (pos - 32) * 8);
        }
        *(uint4*)(&As[row * LDA + pos * 8]) = v;
    }
    __syncthreads();

    int wave = t >> 6, lane = t & 63, lr = lane & 15, lg = lane >> 4;
    float4v acc0 = {0.f,0.f,0.f,0.f}, acc1 = {0.f,0.f,0.f,0.f};
    float4v acc2 = {0.f,0.f,0.f,0.f}, acc3 = {0.f,0.f,0.f,0.f};
    const u16* ar = &As[(wave * 16 + lr) * LDA + lg * 8];
    const uint4* bp = (const uint4*)bsw;
    for (int kt = 0; kt < 10; kt++) {
        short8 a  = *(const short8*)(ar + kt * 32);
        short8 b0 = *(const short8*)(bp + (kt * 4 + 0) * 64 + lane);
        short8 b1 = *(const short8*)(bp + (kt * 4 + 1) * 64 + lane);
        short8 b2 = *(const short8*)(bp + (kt * 4 + 2) * 64 + lane);
        short8 b3 = *(const short8*)(bp + (kt * 4 + 3) * 64 + lane);
        acc0 = __builtin_amdgcn_mfma_f32_16x16x32_bf16(a, b0, acc0, 0, 0, 0);
        acc1 = __builtin_amdgcn_mfma_f32_16x16x32_bf16(a, b1, acc1, 0, 0, 0);
        acc2 = __builtin_amdgcn_mfma_f32_16x16x32_bf16(a, b2, acc2, 0, 0, 0);
        acc3 = __builtin_amdgcn_mfma_f32_16x16x32_bf16(a, b3, acc3, 0, 0, 0);
    }
    float4v accs[4] = {acc0, acc1, acc2, acc3};
#pragma unroll
    for (int ct = 0; ct < 4; ct++) {
        int col = ct * 16 + lr;
        float bv = bias[col];
#pragma unroll
        for (int reg = 0; reg < 4; reg++) {
            int grow = rbase + wave * 16 + lg * 4 + reg;  // C/D: row=(lane>>4)*4+reg, col=lane&15
            if (grow < NN) {
                float v = accs[ct][reg] + bv;
                v = v > 0.f ? v : 0.01f * v;
                xout[(size_t)grow * 64 + col] = f2b(v);
                if (x3out) {
                    float s2 = v + b2f(xadd[(size_t)grow * 64 + col]);
                    x3out[(size_t)grow * 64 + col] = f2b(s2);
                }
            }
        }
    }
}

// ---------------- per-graph node ranges: batch sorted -> boundary scan, no atomics ----------------
__global__ void k_bounds2(const int* __restrict__ batch, int* startg, int* endg) {
    int n = blockIdx.x * blockDim.x + threadIdx.x;
    if (n >= NN) return;
    int b = batch[n];
    if (n == 0) {
        startg[b] = 0;
    } else {
        int bp = batch[n - 1];
        if (bp != b) { startg[b] = n; endg[bp] = n; }
    }
    if (n == NN - 1) endg[b] = NN;
}

// ---------------- pool stage 1: partial max over node slice, concat [x4,x1,x2,x3] ----------------
__global__ __launch_bounds__(256) void k_pool1(const u16* __restrict__ x4, const u16* __restrict__ x1,
                                               const u16* __restrict__ x2, const u16* __restrict__ x3,
                                               const int* __restrict__ startg, const int* __restrict__ endg,
                                               float* __restrict__ partial) {
    int g = blockIdx.x, sl = blockIdx.y;
    int c = threadIdx.x;
    const u16* arr = (c < 64) ? x4 : (c < 128) ? x1 : (c < 192) ? x2 : x3;
    int h = c & 63;
    int s = startg[g], e = endg[g];
    int len = e - s;
    int chunk = (len + NSL - 1) / NSL;
    int s0 = s + sl * chunk;
    int e0 = s0 + chunk; if (e0 > e) e0 = e;
    float m = -3.4e38f;
    for (int n = s0; n < e0; n++) {
        float v = b2f(arr[(size_t)n * 64 + h]);
        m = v > m ? v : m;
    }
    partial[((size_t)g * NSL + sl) * 256 + c] = m;
}

// ---------------- pool stage 2: reduce slices ----------------
__global__ __launch_bounds__(256) void k_pool2(const float* __restrict__ partial,
                                               float* __restrict__ pooled) {
    int g = blockIdx.x, c = threadIdx.x;
    float m = -3.4e38f;
#pragma unroll
    for (int sl = 0; sl < NSL; sl++) {
        float v = partial[((size_t)g * NSL + sl) * 256 + c];
        m = v > m ? v : m;
    }
    pooled[g * 256 + c] = m;
}

// ---------------- final MLP: (50,256)@(256,64) -> BN -> relu -> (64,10), fp32 OUT ----------------
__global__ void k_final(const float* __restrict__ pooled, const float* __restrict__ w1,
                        const float* __restrict__ b1, const float* __restrict__ gamma,
                        const float* __restrict__ beta, const float* __restrict__ w2,
                        const float* __restrict__ b2v, float* __restrict__ out) {
    __shared__ float zsh[64];
    int g = blockIdx.x, h = threadIdx.x;
    float z = b1[h];
    const float* p = pooled + g * 256;
    for (int j = 0; j < 256; j++) z += p[j] * w1[j * 64 + h];
    z = z * 0.9999950000374997f * gamma[h] + beta[h];  // /sqrt(1+1e-5)
    z = z > 0.f ? z : 0.f;
    zsh[h] = z;
    __syncthreads();
    if (h < 10) {
        float o = b2v[h];
        for (int k = 0; k < 64; k++) o += zsh[k] * w2[k * 10 + h];
        out[g * 10 + h] = o;   // fp32 output
    }
}

extern "C" void kernel_launch(void* const* d_in, const int* in_sizes, int n_in,
                              void* d_out, int out_size, void* d_ws, size_t ws_size,
                              hipStream_t stream) {
    const float* x_in    = (const float*)d_in[0];
    const int* ei_raw    = (const int*)d_in[1];
    const int* batch_raw = (const int*)d_in[2];
    const float* eattr   = (const float*)d_in[3];

    const float *g_[4], *mu_[4], *sg_[4], *rw_[4], *b_[4];
    for (int i = 0; i < 4; i++) {
        g_[i]  = (const float*)d_in[4 + 5 * i + 0];
        mu_[i] = (const float*)d_in[4 + 5 * i + 1];
        sg_[i] = (const float*)d_in[4 + 5 * i + 2];
        rw_[i] = (const float*)d_in[4 + 5 * i + 3];
        b_[i]  = (const float*)d_in[4 + 5 * i + 4];
    }
    const float* w_mlp1 = (const float*)d_in[24];
    const float* b_mlp1 = (const float*)d_in[25];
    const float* bn_g   = (const float*)d_in[26];
    const float* bn_b   = (const float*)d_in[27];
    const float* w_mlp2 = (const float*)d_in[28];
    const float* b_mlp2 = (const float*)d_in[29];
    float* out = (float*)d_out;

    // workspace carve-up (~90 MB)
    char* ws = (char*)d_ws;
    size_t o = 0;
    auto take = [&](size_t bytes) { size_t r = o; o += (bytes + 255) & ~(size_t)255; return r; };
    int*   flag     = (int*)(ws + take(4));
    int*   src      = (int*)(ws + take((size_t)NE * 4));
    int*   dst      = (int*)(ws + take((size_t)NE * 4));
    int*   batch32  = (int*)(ws + take((size_t)NN * 4));
    int*   off      = (int*)(ws + take((NN + 1) * 4));
    int*   cnt      = (int*)(ws + take((size_t)NN * 4));
    int*   excl     = (int*)(ws + take((size_t)NSCB * 256 * 4));
    int*   bsum     = (int*)(ws + take((size_t)NSCB * 4));
    int*   ebsum    = (int*)(ws + take(256 * 4));
    uint4* rec      = (uint4*)(ws + take((size_t)NE * 16));
    uint4* arec     = (uint4*)(ws + take((size_t)4 * NE * 16));
    u16*   xb       = (u16*)(ws + take((size_t)NN * 64 * 2));
    u16*   y        = (u16*)(ws + take((size_t)NN * 256 * 2));
    u16*   x0       = (u16*)(ws + take((size_t)NN * 64 * 2));
    u16*   x1       = (u16*)(ws + take((size_t)NN * 64 * 2));
    u16*   x2       = (u16*)(ws + take((size_t)NN * 64 * 2));
    u16*   x3       = (u16*)(ws + take((size_t)NN * 64 * 2));
    u16*   x4       = (u16*)(ws + take((size_t)NN * 64 * 2));
    u16*   bsw      = (u16*)(ws + take((size_t)4 * 320 * 64 * 2));
    float* partial  = (float*)(ws + take((size_t)NG * NSL * 256 * 4));
    float* pooled   = (float*)(ws + take((size_t)NG * 256 * 4));
    int*   startg   = (int*)(ws + take(NG * 4));
    int*   endg     = (int*)(ws + take(NG * 4));
    (void)ws_size; (void)in_sizes; (void)n_in; (void)out_size;

    // index dtype normalization
    k_detect<<<dim3(1), dim3(256), 0, stream>>>(ei_raw, flag);
    k_cvt<<<dim3((NE + 255) / 256), dim3(256), 0, stream>>>(ei_raw, batch_raw, flag, src, dst, batch32);

    // CSR build (parallel scan)
    k_init<<<dim3((NN + 255) / 256), dim3(256), 0, stream>>>(cnt, startg, endg);
    k_hist<<<dim3(NE / 256), dim3(256), 0, stream>>>(dst, cnt);
    k_scanA<<<dim3(NSCB), dim3(256), 0, stream>>>(cnt, excl, bsum);
    k_scanB<<<dim3(1), dim3(256), 0, stream>>>(bsum, ebsum);
    k_scanC<<<dim3(NSCB), dim3(256), 0, stream>>>(excl, ebsum, off);
    k_scatter<<<dim3(NE / 256), dim3(256), 0, stream>>>(src, dst, eattr, off, cnt, rec);
    k_x2b<<<dim3((NN * 64 + 255) / 256), dim3(256), 0, stream>>>(x_in, xb);

    GwParams GP;
    for (int i = 0; i < 4; i++) { GP.mu[i] = mu_[i]; GP.sg[i] = sg_[i]; }
    k_gwpack<<<dim3(NE / 256), dim3(256), 0, stream>>>(rec, GP, arec);

    WParams WP;
    for (int i = 0; i < 4; i++) { WP.g[i] = g_[i]; WP.rw[i] = rw_[i]; }
    k_wprep<<<dim3(4 * 20480 / 256), dim3(256), 0, stream>>>(WP, bsw);

    const int aggGrid = NN / 4;            // 4 waves (nodes) per 256-thr block
    const int gemmGrid = (NN + 63) / 64;   // 64 rows per block

    const u16* lin[4]  = {xb, x0, x1, x3};
    u16*       lout[4] = {x0, x1, x2, x4};
    for (int l = 0; l < 4; l++) {
        k_agg<<<dim3(aggGrid), dim3(256), 0, stream>>>(
            lin[l], arec + (size_t)l * NE, off, y);
        k_gemm<<<dim3(gemmGrid), dim3(256), 0, stream>>>(
            y, lin[l], bsw + (size_t)l * 20480, b_[l], lout[l],
            (l == 2) ? x0 : (const u16*)nullptr,
            (l == 2) ? x3 : (u16*)nullptr);
    }

    k_bounds2<<<dim3((NN + 255) / 256), dim3(256), 0, stream>>>(batch32, startg, endg);
    k_pool1<<<dim3(NG, NSL), dim3(256), 0, stream>>>(x4, x1, x2, x3, startg, endg, partial);
    k_pool2<<<dim3(NG), dim3(256), 0, stream>>>(partial, pooled);
    k_final<<<dim3(NG), dim3(64), 0, stream>>>(pooled, w_mlp1, b_mlp1, bn_g, bn_b, w_mlp2, b_mlp2, out);
}

// Round 11
// 519.791 us; speedup vs baseline: 3.9936x; 1.0932x over previous
//
#include <hip/hip_runtime.h>
#include <hip/hip_bf16.h>

#define NN 50000
#define NE 800000
#define NG 50
#define NSL 16    // pool slices per graph
#define NSCB 196  // scan blocks (196*256 = 50176 >= NN+1)

typedef unsigned short u16;
typedef unsigned int u32;
typedef __attribute__((ext_vector_type(8))) short short8;
typedef __attribute__((ext_vector_type(4))) float float4v;

__device__ __forceinline__ float b2f(u16 u) {
    union { u32 i; float f; } v; v.i = ((u32)u) << 16; return v.f;
}
__device__ __forceinline__ u16 f2b(float f) {
    union { float f; u32 i; } v; v.f = f;
    u32 i = v.i;
    return (u16)((i + 0x7FFFu + ((i >> 16) & 1u)) >> 16);
}

// ---------------- detect int64 vs int32 edge_index encoding (parallel) ----------------
__global__ void k_detect(const int* __restrict__ ei_raw, int* flag) {
    __shared__ int cs[256];
    int t = threadIdx.x;
    cs[t] = (ei_raw[2 * t + 1] == 0) ? 1 : 0;
    __syncthreads();
    for (int d = 128; d > 0; d >>= 1) {
        if (t < d) cs[t] += cs[t + d];
        __syncthreads();
    }
    if (t == 0) *flag = (cs[0] >= 128) ? 1 : 0;
}

// ---------------- convert edge_index & batch to int32 ----------------
__global__ void k_cvt(const int* __restrict__ ei_raw, const int* __restrict__ batch_raw,
                      const int* __restrict__ flag, int* __restrict__ src,
                      int* __restrict__ dst, int* __restrict__ batch32) {
    int i = blockIdx.x * blockDim.x + threadIdx.x;
    int w = *flag;
    if (i < NE) {
        if (w) { src[i] = ei_raw[2 * i]; dst[i] = ei_raw[2 * (NE + i)]; }
        else   { src[i] = ei_raw[i];     dst[i] = ei_raw[NE + i]; }
    }
    if (i < NN) batch32[i] = w ? batch_raw[2 * i] : batch_raw[i];
}

// ---------------- init ----------------
__global__ void k_init(int* cnt, int* startg, int* endg) {
    int i = blockIdx.x * blockDim.x + threadIdx.x;
    if (i < NN) cnt[i] = 0;
    if (i < NG) { startg[i] = 0x7fffffff; endg[i] = 0; }
}

// ---------------- histogram of dst ----------------
__global__ void k_hist(const int* __restrict__ dst, int* cnt) {
    int e = blockIdx.x * blockDim.x + threadIdx.x;
    if (e < NE) atomicAdd(&cnt[dst[e]], 1);
}

// ---------------- scan stage A: block-local exclusive scan + block sums; zero cnt ----------------
__global__ __launch_bounds__(256) void k_scanA(int* __restrict__ cnt, int* __restrict__ excl,
                                               int* __restrict__ bsum) {
    __shared__ int s[256];
    int t = threadIdx.x, b = blockIdx.x;
    int i = b * 256 + t;
    int v = (i < NN) ? cnt[i] : 0;
    s[t] = v; __syncthreads();
    for (int d = 1; d < 256; d <<= 1) {
        int x = s[t];
        int y = (t >= d) ? s[t - d] : 0;
        __syncthreads();
        s[t] = x + y;
        __syncthreads();
    }
    excl[i] = s[t] - v;               // exclusive prefix within block
    if (t == 255) bsum[b] = s[255];   // block total
    if (i < NN) cnt[i] = 0;           // reset for scatter cursor
}

// ---------------- scan stage B: exclusive scan of block sums ----------------
__global__ __launch_bounds__(256) void k_scanB(const int* __restrict__ bsum, int* __restrict__ ebsum) {
    __shared__ int s[256];
    int t = threadIdx.x;
    int v = (t < NSCB) ? bsum[t] : 0;
    s[t] = v; __syncthreads();
    for (int d = 1; d < 256; d <<= 1) {
        int x = s[t];
        int y = (t >= d) ? s[t - d] : 0;
        __syncthreads();
        s[t] = x + y;
        __syncthreads();
    }
    ebsum[t] = s[t] - v;
}

// ---------------- scan stage C: combine ----------------
__global__ void k_scanC(const int* __restrict__ excl, const int* __restrict__ ebsum,
                        int* __restrict__ off) {
    int i = blockIdx.x * blockDim.x + threadIdx.x;
    if (i <= NN) off[i] = excl[i] + ebsum[i >> 8];
}

// ---------------- scatter edges into CSR-by-dst, ONE 16B record per edge ----------------
__global__ void k_scatter(const int* __restrict__ src, const int* __restrict__ dst,
                          const float* __restrict__ eattr, const int* __restrict__ off,
                          int* cur, uint4* __restrict__ rec) {
    int e = blockIdx.x * blockDim.x + threadIdx.x;
    if (e >= NE) return;
    int d = dst[e];
    int p = atomicAdd(&cur[d], 1);
    int slot = off[d] + p;
    uint4 r;
    r.x = (u32)src[e];
    r.y = __float_as_uint(eattr[2 * e]);
    r.z = __float_as_uint(eattr[2 * e + 1]);
    r.w = 0;
    rec[slot] = r;
}

// ---------------- x (f32) -> bf16 ----------------
__global__ void k_x2b(const float* __restrict__ x, u16* __restrict__ xb) {
    int i = blockIdx.x * blockDim.x + threadIdx.x;
    if (i < NN * 64) xb[i] = f2b(x[i]);
}

// ---------------- gw pack: all 4 layers in one pass; per layer {src, gw01, gw23, 0} 16B ----------------
struct GwParams { const float* mu[4]; const float* sg[4]; };
__global__ __launch_bounds__(256) void k_gwpack(const uint4* __restrict__ rec, GwParams P,
                                                uint4* __restrict__ arec) {
    int j = blockIdx.x * blockDim.x + threadIdx.x;
    if (j >= NE) return;
    uint4 r = rec[j];
    float a0 = __uint_as_float(r.y), a1 = __uint_as_float(r.z);
#pragma unroll
    for (int l = 0; l < 4; l++) {
        u32 p01, p23;
        {
            u16 w[4];
#pragma unroll
            for (int k = 0; k < 4; k++) {
                float d0 = a0 - P.mu[l][2 * k], d1 = a1 - P.mu[l][2 * k + 1];
                float s0 = P.sg[l][2 * k], s1 = P.sg[l][2 * k + 1];
                float t = d0 * d0 / (1e-15f + s0 * s0) + d1 * d1 / (1e-15f + s1 * s1);
                w[k] = f2b(expf(-0.5f * t));
            }
            p01 = (u32)w[0] | ((u32)w[1] << 16);
            p23 = (u32)w[2] | ((u32)w[3] << 16);
        }
        uint4 o; o.x = r.x; o.y = p01; o.z = p23; o.w = 0;
        arec[(size_t)l * NE + j] = o;
    }
}

// ---------------- pre-swizzle Wcat=[G2;rw] (f32) into bf16 MFMA B-fragment order ----------------
struct WParams { const float* g[4]; const float* rw[4]; };
__global__ void k_wprep(WParams P, u16* __restrict__ bsw) {
    int id = blockIdx.x * blockDim.x + threadIdx.x;
    if (id >= 4 * 20480) return;
    int l = id / 20480, r = id % 20480;
    int j = r & 7, lane = (r >> 3) & 63, ctkt = r >> 9;
    int ct = ctkt & 3, kt = ctkt >> 2;
    int k = kt * 32 + (lane >> 4) * 8 + j;
    int n = ct * 16 + (lane & 15);
    float v;
    if (k < 256) v = P.g[l][(k & 63) * 256 + (k >> 6) * 64 + n];  // G2[k][n] = g[d][kk*64+n]
    else         v = P.rw[l][(k - 256) * 64 + n];
    bsw[id] = f2b(v);
}

// ---------------- aggregation: y[n][k*64+d] = (1/deg) sum_e gw[e][k]*x[src][d] ----------------
// one wave per node; 4 edge-groups x 16 lanes; lane covers 4 features (8B loads)
__global__ __launch_bounds__(256) void k_agg(const u16* __restrict__ xin,
                                             const uint4* __restrict__ arec,
                                             const int* __restrict__ off,
                                             u16* __restrict__ y) {
    int wid = (blockIdx.x * 256 + threadIdx.x) >> 6;  // node, one wave each
    int lane = threadIdx.x & 63;
    int g = lane >> 4;        // edge group 0..3
    int f = lane & 15;        // feature quad: features 4f..4f+3
    if (wid >= NN) return;
    int beg = off[wid], end = off[wid + 1];
    float acc[4][4];
#pragma unroll
    for (int k = 0; k < 4; k++)
#pragma unroll
        for (int i = 0; i < 4; i++) acc[k][i] = 0.f;

    int niter = (end - beg + 3) >> 2;
    for (int it = 0; it < niter; it++) {
        int j = beg + it * 4 + g;
        uint4 r = make_uint4(0, 0, 0, 0);           // tail: gw=0, src=0 (row 0 valid)
        if (j < end) r = arec[j];
        uint2 xr = *(const uint2*)(xin + (size_t)r.x * 64 + f * 4);
        float x0 = b2f((u16)(xr.x & 0xffffu)), x1 = b2f((u16)(xr.x >> 16));
        float x2 = b2f((u16)(xr.y & 0xffffu)), x3 = b2f((u16)(xr.y >> 16));
        float w0 = b2f((u16)(r.y & 0xffffu)), w1 = b2f((u16)(r.y >> 16));
        float w2 = b2f((u16)(r.z & 0xffffu)), w3 = b2f((u16)(r.z >> 16));
        acc[0][0] += w0 * x0; acc[0][1] += w0 * x1; acc[0][2] += w0 * x2; acc[0][3] += w0 * x3;
        acc[1][0] += w1 * x0; acc[1][1] += w1 * x1; acc[1][2] += w1 * x2; acc[1][3] += w1 * x3;
        acc[2][0] += w2 * x0; acc[2][1] += w2 * x1; acc[2][2] += w2 * x2; acc[2][3] += w2 * x3;
        acc[3][0] += w3 * x0; acc[3][1] += w3 * x1; acc[3][2] += w3 * x2; acc[3][3] += w3 * x3;
    }

    // reduce across the 4 edge-groups (lanes differing in bits 4,5)
#pragma unroll
    for (int k = 0; k < 4; k++)
#pragma unroll
        for (int i = 0; i < 4; i++) {
            float v = acc[k][i];
            v += __shfl_xor(v, 16, 64);
            v += __shfl_xor(v, 32, 64);
            acc[k][i] = v;
        }

    int deg = end - beg;
    float sc = 1.0f / (float)(deg > 1 ? deg : 1);
    // group g writes k=g's feature quad as one packed 8B store
    u16 o0 = f2b(acc[g][0] * sc), o1 = f2b(acc[g][1] * sc);
    u16 o2 = f2b(acc[g][2] * sc), o3 = f2b(acc[g][3] * sc);
    uint2 pk;
    pk.x = (u32)o0 | ((u32)o1 << 16);
    pk.y = (u32)o2 | ((u32)o3 << 16);
    *(uint2*)(y + (size_t)wid * 256 + g * 64 + f * 4) = pk;
}

// ---------------- GEMM: xout = lrelu([y|xin](N,320) @ Wcat(320,64) + b); opt x3 = x0 + xout ----------------
#define LDA 328  // 320 + 8 u16 pad -> rows 656B, 16B aligned
__global__ __launch_bounds__(256) void k_gemm(const u16* __restrict__ y,
                                              const u16* __restrict__ xin,
                                              const u16* __restrict__ bsw,
                                              const float* __restrict__ bias,
                                              u16* __restrict__ xout,
                                              const u16* __restrict__ xadd,
                                              u16* __restrict__ x3out) {
    __shared__ u16 As[64 * LDA];
    int t = threadIdx.x;
    int rbase = blockIdx.x * 64;
#pragma unroll
    for (int c = 0; c < 10; c++) {
        int idx = t + c * 256;
        int row = idx / 40, pos = idx % 40;
        int grow = rbase + row;
        uint4 v = make_uint4(0, 0, 0, 0);
        if (grow < NN) {
            if (pos < 32) v = *(const uint4*)(y + (size_t)grow * 256 + pos * 8);
            else          v = *(const uint4*)(xin + (size_t)grow * 64 + (pos - 32) * 8);
        }
        *(uint4*)(&As[row * LDA + pos * 8]) = v;
    }
    __syncthreads();

    int wave = t >> 6, lane = t & 63, lr = lane & 15, lg = lane >> 4;
    float4v acc0 = {0.f,0.f,0.f,0.f}, acc1 = {0.f,0.f,0.f,0.f};
    float4v acc2 = {0.f,0.f,0.f,0.f}, acc3 = {0.f,0.f,0.f,0.f};
    const u16* ar = &As[(wave * 16 + lr) * LDA + lg * 8];
    const uint4* bp = (const uint4*)bsw;
    for (int kt = 0; kt < 10; kt++) {
        short8 a  = *(const short8*)(ar + kt * 32);
        short8 b0 = *(const short8*)(bp + (kt * 4 + 0) * 64 + lane);
        short8 b1 = *(const short8*)(bp + (kt * 4 + 1) * 64 + lane);
        short8 b2 = *(const short8*)(bp + (kt * 4 + 2) * 64 + lane);
        short8 b3 = *(const short8*)(bp + (kt * 4 + 3) * 64 + lane);
        acc0 = __builtin_amdgcn_mfma_f32_16x16x32_bf16(a, b0, acc0, 0, 0, 0);
        acc1 = __builtin_amdgcn_mfma_f32_16x16x32_bf16(a, b1, acc1, 0, 0, 0);
        acc2 = __builtin_amdgcn_mfma_f32_16x16x32_bf16(a, b2, acc2, 0, 0, 0);
        acc3 = __builtin_amdgcn_mfma_f32_16x16x32_bf16(a, b3, acc3, 0, 0, 0);
    }
    float4v accs[4] = {acc0, acc1, acc2, acc3};
#pragma unroll
    for (int ct = 0; ct < 4; ct++) {
        int col = ct * 16 + lr;
        float bv = bias[col];
#pragma unroll
        for (int reg = 0; reg < 4; reg++) {
            int grow = rbase + wave * 16 + lg * 4 + reg;  // C/D: row=(lane>>4)*4+reg, col=lane&15
            if (grow < NN) {
                float v = accs[ct][reg] + bv;
                v = v > 0.f ? v : 0.01f * v;
                xout[(size_t)grow * 64 + col] = f2b(v);
                if (x3out) {
                    float s2 = v + b2f(xadd[(size_t)grow * 64 + col]);
                    x3out[(size_t)grow * 64 + col] = f2b(s2);
                }
            }
        }
    }
}

// ---------------- per-graph node ranges: batch sorted -> boundary scan, no atomics ----------------
__global__ void k_bounds2(const int* __restrict__ batch, int* startg, int* endg) {
    int n = blockIdx.x * blockDim.x + threadIdx.x;
    if (n >= NN) return;
    int b = batch[n];
    if (n == 0) {
        startg[b] = 0;
    } else {
        int bp = batch[n - 1];
        if (bp != b) { startg[b] = n; endg[bp] = n; }
    }
    if (n == NN - 1) endg[b] = NN;
}

// ---------------- pool stage 1: partial max over node slice, concat [x4,x1,x2,x3] ----------------
__global__ __launch_bounds__(256) void k_pool1(const u16* __restrict__ x4, const u16* __restrict__ x1,
                                               const u16* __restrict__ x2, const u16* __restrict__ x3,
                                               const int* __restrict__ startg, const int* __restrict__ endg,
                                               float* __restrict__ partial) {
    int g = blockIdx.x, sl = blockIdx.y;
    int c = threadIdx.x;
    const u16* arr = (c < 64) ? x4 : (c < 128) ? x1 : (c < 192) ? x2 : x3;
    int h = c & 63;
    int s = startg[g], e = endg[g];
    int len = e - s;
    int chunk = (len + NSL - 1) / NSL;
    int s0 = s + sl * chunk;
    int e0 = s0 + chunk; if (e0 > e) e0 = e;
    float m = -3.4e38f;
    for (int n = s0; n < e0; n++) {
        float v = b2f(arr[(size_t)n * 64 + h]);
        m = v > m ? v : m;
    }
    partial[((size_t)g * NSL + sl) * 256 + c] = m;
}

// ---------------- pool stage 2: reduce slices ----------------
__global__ __launch_bounds__(256) void k_pool2(const float* __restrict__ partial,
                                               float* __restrict__ pooled) {
    int g = blockIdx.x, c = threadIdx.x;
    float m = -3.4e38f;
#pragma unroll
    for (int sl = 0; sl < NSL; sl++) {
        float v = partial[((size_t)g * NSL + sl) * 256 + c];
        m = v > m ? v : m;
    }
    pooled[g * 256 + c] = m;
}

// ---------------- final MLP: (50,256)@(256,64) -> BN -> relu -> (64,10), fp32 OUT ----------------
__global__ void k_final(const float* __restrict__ pooled, const float* __restrict__ w1,
                        const float* __restrict__ b1, const float* __restrict__ gamma,
                        const float* __restrict__ beta, const float* __restrict__ w2,
                        const float* __restrict__ b2v, float* __restrict__ out) {
    __shared__ float zsh[64];
    int g = blockIdx.x, h = threadIdx.x;
    float z = b1[h];
    const float* p = pooled + g * 256;
    for (int j = 0; j < 256; j++) z += p[j] * w1[j * 64 + h];
    z = z * 0.9999950000374997f * gamma[h] + beta[h];  // /sqrt(1+1e-5)
    z = z > 0.f ? z : 0.f;
    zsh[h] = z;
    __syncthreads();
    if (h < 10) {
        float o = b2v[h];
        for (int k = 0; k < 64; k++) o += zsh[k] * w2[k * 10 + h];
        out[g * 10 + h] = o;   // fp32 output
    }
}

extern "C" void kernel_launch(void* const* d_in, const int* in_sizes, int n_in,
                              void* d_out, int out_size, void* d_ws, size_t ws_size,
                              hipStream_t stream) {
    const float* x_in    = (const float*)d_in[0];
    const int* ei_raw    = (const int*)d_in[1];
    const int* batch_raw = (const int*)d_in[2];
    const float* eattr   = (const float*)d_in[3];

    const float *g_[4], *mu_[4], *sg_[4], *rw_[4], *b_[4];
    for (int i = 0; i < 4; i++) {
        g_[i]  = (const float*)d_in[4 + 5 * i + 0];
        mu_[i] = (const float*)d_in[4 + 5 * i + 1];
        sg_[i] = (const float*)d_in[4 + 5 * i + 2];
        rw_[i] = (const float*)d_in[4 + 5 * i + 3];
        b_[i]  = (const float*)d_in[4 + 5 * i + 4];
    }
    const float* w_mlp1 = (const float*)d_in[24];
    const float* b_mlp1 = (const float*)d_in[25];
    const float* bn_g   = (const float*)d_in[26];
    const float* bn_b   = (const float*)d_in[27];
    const float* w_mlp2 = (const float*)d_in[28];
    const float* b_mlp2 = (const float*)d_in[29];
    float* out = (float*)d_out;

    // workspace carve-up (~90 MB)
    char* ws = (char*)d_ws;
    size_t o = 0;
    auto take = [&](size_t bytes) { size_t r = o; o += (bytes + 255) & ~(size_t)255; return r; };
    int*   flag     = (int*)(ws + take(4));
    int*   src      = (int*)(ws + take((size_t)NE * 4));
    int*   dst      = (int*)(ws + take((size_t)NE * 4));
    int*   batch32  = (int*)(ws + take((size_t)NN * 4));
    int*   off      = (int*)(ws + take((NN + 1) * 4));
    int*   cnt      = (int*)(ws + take((size_t)NN * 4));
    int*   excl     = (int*)(ws + take((size_t)NSCB * 256 * 4));
    int*   bsum     = (int*)(ws + take((size_t)NSCB * 4));
    int*   ebsum    = (int*)(ws + take(256 * 4));
    uint4* rec      = (uint4*)(ws + take((size_t)NE * 16));
    uint4* arec     = (uint4*)(ws + take((size_t)4 * NE * 16));
    u16*   xb       = (u16*)(ws + take((size_t)NN * 64 * 2));
    u16*   y        = (u16*)(ws + take((size_t)NN * 256 * 2));
    u16*   x0       = (u16*)(ws + take((size_t)NN * 64 * 2));
    u16*   x1       = (u16*)(ws + take((size_t)NN * 64 * 2));
    u16*   x2       = (u16*)(ws + take((size_t)NN * 64 * 2));
    u16*   x3       = (u16*)(ws + take((size_t)NN * 64 * 2));
    u16*   x4       = (u16*)(ws + take((size_t)NN * 64 * 2));
    u16*   bsw      = (u16*)(ws + take((size_t)4 * 320 * 64 * 2));
    float* partial  = (float*)(ws + take((size_t)NG * NSL * 256 * 4));
    float* pooled   = (float*)(ws + take((size_t)NG * 256 * 4));
    int*   startg   = (int*)(ws + take(NG * 4));
    int*   endg     = (int*)(ws + take(NG * 4));
    (void)ws_size; (void)in_sizes; (void)n_in; (void)out_size;

    // index dtype normalization
    k_detect<<<dim3(1), dim3(256), 0, stream>>>(ei_raw, flag);
    k_cvt<<<dim3((NE + 255) / 256), dim3(256), 0, stream>>>(ei_raw, batch_raw, flag, src, dst, batch32);

    // CSR build (parallel scan)
    k_init<<<dim3((NN + 255) / 256), dim3(256), 0, stream>>>(cnt, startg, endg);
    k_hist<<<dim3(NE / 256), dim3(256), 0, stream>>>(dst, cnt);
    k_scanA<<<dim3(NSCB), dim3(256), 0, stream>>>(cnt, excl, bsum);
    k_scanB<<<dim3(1), dim3(256), 0, stream>>>(bsum, ebsum);
    k_scanC<<<dim3(NSCB), dim3(256), 0, stream>>>(excl, ebsum, off);
    k_scatter<<<dim3(NE / 256), dim3(256), 0, stream>>>(src, dst, eattr, off, cnt, rec);
    k_x2b<<<dim3((NN * 64 + 255) / 256), dim3(256), 0, stream>>>(x_in, xb);

    GwParams GP;
    for (int i = 0; i < 4; i++) { GP.mu[i] = mu_[i]; GP.sg[i] = sg_[i]; }
    k_gwpack<<<dim3(NE / 256), dim3(256), 0, stream>>>(rec, GP, arec);

    WParams WP;
    for (int i = 0; i < 4; i++) { WP.g[i] = g_[i]; WP.rw[i] = rw_[i]; }
    k_wprep<<<dim3(4 * 20480 / 256), dim3(256), 0, stream>>>(WP, bsw);

    const int aggGrid = NN / 4;            // 4 waves (nodes) per 256-thr block
    const int gemmGrid = (NN + 63) / 64;   // 64 rows per block

    const u16* lin[4]  = {xb, x0, x1, x3};
    u16*       lout[4] = {x0, x1, x2, x4};
    for (int l = 0; l < 4; l++) {
        k_agg<<<dim3(aggGrid), dim3(256), 0, stream>>>(
            lin[l], arec + (size_t)l * NE, off, y);
        k_gemm<<<dim3(gemmGrid), dim3(256), 0, stream>>>(
            y, lin[l], bsw + (size_t)l * 20480, b_[l], lout[l],
            (l == 2) ? x0 : (const u16*)nullptr,
            (l == 2) ? x3 : (u16*)nullptr);
    }

    k_bounds2<<<dim3((NN + 255) / 256), dim3(256), 0, stream>>>(batch32, startg, endg);
    k_pool1<<<dim3(NG, NSL), dim3(256), 0, stream>>>(x4, x1, x2, x3, startg, endg, partial);
    k_pool2<<<dim3(NG), dim3(256), 0, stream>>>(partial, pooled);
    k_final<<<dim3(NG), dim3(64), 0, stream>>>(pooled, w_mlp1, b_mlp1, bn_g, bn_b, w_mlp2, b_mlp2, out);
}